// Round 6
// baseline (1777.568 us; speedup 1.0000x reference)
//
#include <hip/hip_runtime.h>
#include <hip/hip_bf16.h>
#include <math.h>

// ---------------------------------------------------------------------------
// D=256, LVL=17, MIX=20. N nodes = 2^18-1; internal = 2^17-1 = 131071.
//  * Encoder reads ORIGINAL Feature -> only root's encoded feature survives.
//  * Decoder: 17 sequential levels; level l has B=2^l nodes. X_P dead.
// R6: proven R4 3-kernel pipeline for levels 6..16; levels 0..5 fused into a
//     single-block kernel (phases A-D, __syncthreads only, regular launch).
//     Single pack_all. No cooperative launch (R5's silent-failure suspect).
// ---------------------------------------------------------------------------

#define LOG2PI 1.8378770664093453f

typedef __attribute__((ext_vector_type(8))) short short8;
typedef __attribute__((ext_vector_type(4))) float f32x4;

__device__ inline float sigm(float x) { return 1.0f / (1.0f + expf(-x)); }

__device__ inline ushort f2b(float v) {
    union { float f; unsigned u; } x; x.f = v;
    unsigned r = x.u + 0x7fffu + ((x.u >> 16) & 1u);
    return (ushort)(r >> 16);
}
__device__ inline float b2f(ushort h) {
    union { unsigned u; float f; } x; x.u = ((unsigned)h) << 16; return x.f;
}

__device__ inline void gload16(const void* g, void* l) {
    __builtin_amdgcn_global_load_lds(
        (const __attribute__((address_space(1))) unsigned*)g,
        (__attribute__((address_space(3))) unsigned*)l, 16, 0, 0);
}

__device__ inline f32x4 mfma16(short8 a, short8 b, f32x4 c) {
    return __builtin_amdgcn_mfma_f32_16x16x32_bf16(a, b, c, 0, 0, 0);
}

__device__ inline float halfmax(float v) {
    #pragma unroll
    for (int o = 16; o >= 1; o >>= 1) v = fmaxf(v, __shfl_xor(v, o));
    return v;
}
__device__ inline float halfsum(float v) {
    #pragma unroll
    for (int o = 16; o >= 1; o >>= 1) v += __shfl_xor(v, o);
    return v;
}
__device__ inline float lse20(float t) {
    float m = halfmax(t);
    float s = halfsum(expf(t - m));
    return m + logf(s);
}

// NLL for one node; yb = this half's 263-float Y row. Wave-collective.
__device__ inline float nll_node(const float* yb, const float* X,
                                 long long fi, int lane, bool& sw_out)
{
    const int half = lane >> 5, k = lane & 31;
    float v = (k < 20) ? yb[k] : -INFINITY;
    float mm = halfmax(v);
    float se = halfsum((k < 20) ? expf(v - mm) : 0.f);
    float lpi = v - mm - logf(se);
    float mx = 0, my = 0, sx = 1, sy = 1, rho = 0, omr = 1, cxy = 0;
    float ma = 0, mb2 = 0, sa = 1, sb = 1, rab = 0, omr2 = 1, cab = 0;
    float ms = 0, ss2 = 1, csl = 0;
    if (k < 20) {
        mx = yb[20 + k]; my = yb[40 + k];
        float lsx = yb[60 + k], lsy = yb[80 + k];
        sx = expf(lsx); sy = expf(lsy);
        rho = tanhf(yb[100 + k]); omr = 1.f - rho * rho;
        cxy = LOG2PI + lsx + lsy + 0.5f * logf(omr);
        ma = yb[120 + k]; mb2 = yb[140 + k];
        float lsa = yb[160 + k], lsb = yb[180 + k];
        sa = expf(lsa); sb = expf(lsb);
        rab = tanhf(yb[200 + k]); omr2 = 1.f - rab * rab;
        cab = LOG2PI + lsa + lsb + 0.5f * logf(omr2);
        ms = yb[220 + k]; float lss = yb[240 + k];
        ss2 = expf(lss);
        csl = 0.5f * LOG2PI + lss;
    }
    float lq0, lq1, lq2;
    {
        float q0 = yb[260], q1 = yb[261], q2 = yb[262];
        float qm = fmaxf(q0, fmaxf(q1, q2));
        float l = logf(expf(q0 - qm) + expf(q1 - qm) + expf(q2 - qm)) + qm;
        lq0 = q0 - l; lq1 = q1 - l; lq2 = q2 - l;
    }
    const float* pl = X + (size_t)(2 * fi + 1) * 8;
    const float* pr = X + (size_t)(2 * fi + 2) * 8;
    float res[2];
    #pragma unroll
    for (int s = 0; s < 2; ++s) {
        const float* pt = s ? pr : pl;
        float dx = pt[0], dy = pt[1], da = pt[2], db = pt[3], ds = pt[4];
        float t1 = -INFINITY, t2 = -INFINITY, t3 = -INFINITY;
        if (k < 20) {
            float zx = (dx - mx) / sx, zy = (dy - my) / sy;
            float Zz = zx * zx + zy * zy - 2.f * rho * zx * zy;
            t1 = lpi - Zz / (2.f * omr) - cxy;
            float za = (da - ma) / sa, zb = (db - mb2) / sb;
            float Z2 = za * za + zb * zb - 2.f * rab * za * zb;
            t2 = lpi - Z2 / (2.f * omr2) - cab;
            float zs = ds - ms;
            t3 = lpi - (zs * zs) / (2.f * ss2 * ss2) - csl;
        }
        float l1 = lse20(t1), l2 = lse20(t2), l3 = lse20(t3);
        float pen = -(pt[5] * lq0 + pt[6] * lq1 + pt[7] * lq2);
        res[s] = -(l1 + l2 + l3) + pen;
    }
    float Aval = half ? res[1] : res[0];
    float Bval = half ? res[0] : res[1];
    float direct = Aval + __shfl_xor(Aval, 32);
    float swapped = Bval + __shfl_xor(Bval, 32);
    sw_out = swapped < direct;
    return sw_out ? swapped : direct;
}

__device__ inline void feat_write(ushort* FeatNext, const ushort* Hj,
                                  const ushort* Cj, long long j, bool sw, int lane)
{
    const size_t Jg = 2 * (size_t)j;
    const int offL = sw ? 128 : 0;
    const int offR = 128 - offL;
    const int part = lane >> 5;
    const int c = (lane & 31) * 4;
    ushort4 vL = *(const ushort4*)((part ? Cj : Hj) + offL + c);
    ushort4 vR = *(const ushort4*)((part ? Cj : Hj) + offR + c);
    *(ushort4*)(FeatNext + Jg * 256 + part * 128 + c) = vL;
    *(ushort4*)(FeatNext + (Jg + 1) * 256 + part * 128 + c) = vR;
}

// ---------------------------------------------------------------------------
// bf16 NT GEMM (Z): C = tanh(A @ B^T + bias) -> bf16. K templated+unrolled.
// ---------------------------------------------------------------------------
template <int ACT, int OUT_MODE, int KK>
__global__ __launch_bounds__(256) void gemm_bf16(
    const ushort* __restrict__ A, int lda, int Mclamp,
    const ushort* __restrict__ B, int ldb, int Nclamp,
    const float* __restrict__ bias0,
    float* __restrict__ Cf, ushort* __restrict__ Cb, int ldc,
    int M, int N)
{
    __shared__ ushort As[128 * 64];
    __shared__ ushort Bs[128 * 64];
    const int tid = threadIdx.x;
    const int lane = tid & 63;
    const int w = tid >> 6;
    const int wr = w >> 1, wc = w & 1;
    const int fr = lane & 15, fq = lane >> 4;
    const int m0 = blockIdx.x * 128, n0 = blockIdx.y * 128;

    f32x4 acc[4][4] = {};

    #pragma unroll
    for (int k0 = 0; k0 < KK; k0 += 64) {
        __syncthreads();
        #pragma unroll
        for (int it = 0; it < 4; ++it) {
            const int i = it * 256 + tid;
            const int row = i >> 3, slot = i & 7;
            const int sl = slot ^ (row & 7);
            const int wbase = (i - lane) * 8;
            {
                int gm = m0 + row; gm = gm <= Mclamp ? gm : Mclamp;
                gload16(A + (size_t)gm * lda + k0 + sl * 8, &As[wbase]);
            }
            {
                int gn = n0 + row; gn = gn <= Nclamp ? gn : Nclamp;
                gload16(B + (size_t)gn * ldb + k0 + sl * 8, &Bs[wbase]);
            }
        }
        __syncthreads();
        #pragma unroll
        for (int ks = 0; ks < 2; ++ks) {
            short8 af[4], bfr[4];
            #pragma unroll
            for (int mr = 0; mr < 4; ++mr) {
                const int row = wr * 64 + mr * 16 + fr;
                const int sl = (ks * 4 + fq) ^ (row & 7);
                af[mr] = *(const short8*)&As[row * 64 + sl * 8];
            }
            #pragma unroll
            for (int nc = 0; nc < 4; ++nc) {
                const int row = wc * 64 + nc * 16 + fr;
                const int sl = (ks * 4 + fq) ^ (row & 7);
                bfr[nc] = *(const short8*)&Bs[row * 64 + sl * 8];
            }
            #pragma unroll
            for (int mr = 0; mr < 4; ++mr)
                #pragma unroll
                for (int nc = 0; nc < 4; ++nc)
                    acc[mr][nc] = mfma16(af[mr], bfr[nc], acc[mr][nc]);
        }
    }

    #pragma unroll
    for (int mr = 0; mr < 4; ++mr) {
        #pragma unroll
        for (int j = 0; j < 4; ++j) {
            const int row = m0 + wr * 64 + mr * 16 + fq * 4 + j;
            if (row >= M) continue;
            #pragma unroll
            for (int nc = 0; nc < 4; ++nc) {
                const int col = n0 + wc * 64 + nc * 16 + fr;
                if (col >= N) continue;
                float v = acc[mr][nc][j] + bias0[col];
                if (ACT == 1) v = tanhf(v);
                if (OUT_MODE == 0) Cf[(size_t)row * ldc + col] = v;
                else               Cb[(size_t)row * ldc + col] = f2b(v);
            }
        }
    }
}

// ---------------------------------------------------------------------------
// Fused gates GEMM + LSTM epilogue (levels 6..16). k0 fully unrolled.
// ---------------------------------------------------------------------------
__global__ __launch_bounds__(256) void gates_lstm(
    const ushort* __restrict__ Xb,
    const ushort* __restrict__ Fcur,
    const ushort* __restrict__ Zb,
    const ushort* __restrict__ Wg,
    const float*  __restrict__ bg,
    ushort* __restrict__ H, ushort* __restrict__ C, int M)
{
    __shared__ ushort As[128 * 64];
    __shared__ ushort Bs[128 * 64];
    const int tid = threadIdx.x;
    const int lane = tid & 63;
    const int w = tid >> 6;
    const int wr = w >> 1, wc = w & 1;
    const int fr = lane & 15, fq = lane >> 4;
    const int m0 = blockIdx.x * 128, n0 = blockIdx.y * 128;

    f32x4 acc[4][4] = {};

    #pragma unroll
    for (int k0 = 0; k0 < 576; k0 += 64) {
        __syncthreads();
        const int sbase = k0 >> 3;
        #pragma unroll
        for (int it = 0; it < 4; ++it) {
            const int i = it * 256 + tid;
            const int row = i >> 3, slot = i & 7;
            const int sl = slot ^ (row & 7);
            const int wbase = (i - lane) * 8;
            {
                int gm = m0 + row; gm = gm < M ? gm : M - 1;
                const int a = sbase + sl;
                const ushort* src;
                if (a == 0)      src = Xb   + (size_t)gm * 8;
                else if (a < 33) src = Fcur + (size_t)gm * 256 + (size_t)(a - 1) * 8;
                else if (a < 65) src = Zb   + (size_t)gm * 512 + (size_t)(a - 33) * 8;
                else             src = Zb   + (size_t)gm * 512;   // junk; Wg cols zero
                gload16(src, &As[wbase]);
            }
            gload16(Wg + (size_t)(n0 + row) * 576 + k0 + sl * 8, &Bs[wbase]);
        }
        __syncthreads();
        #pragma unroll
        for (int ks = 0; ks < 2; ++ks) {
            short8 af[4], bfr[4];
            #pragma unroll
            for (int mr = 0; mr < 4; ++mr) {
                const int row = wr * 64 + mr * 16 + fr;
                const int sl = (ks * 4 + fq) ^ (row & 7);
                af[mr] = *(const short8*)&As[row * 64 + sl * 8];
            }
            #pragma unroll
            for (int nc = 0; nc < 4; ++nc) {
                const int row = wc * 64 + nc * 16 + fr;
                const int sl = (ks * 4 + fq) ^ (row & 7);
                bfr[nc] = *(const short8*)&Bs[row * 64 + sl * 8];
            }
            #pragma unroll
            for (int mr = 0; mr < 4; ++mr)
                #pragma unroll
                for (int nc = 0; nc < 4; ++nc)
                    acc[mr][nc] = mfma16(af[mr], bfr[nc], acc[mr][nc]);
        }
    }

    const int q = fr & 3;
    #pragma unroll
    for (int mr = 0; mr < 4; ++mr) {
        const int node = m0 + wr * 64 + mr * 16 + fq * 4 + q;
        #pragma unroll
        for (int nc = 0; nc < 4; ++nc) {
            const int col = n0 + wc * 64 + nc * 16 + fr;
            f32x4 v = acc[mr][nc];
            const float b = bg[col];
            v[0] += b; v[1] += b; v[2] += b; v[3] += b;
            float gv[4];
            gv[q] = v[q];
            #pragma unroll
            for (int m = 1; m < 4; ++m)
                gv[q ^ m] = __shfl_xor(v[q ^ m], m);
            if (node < M) {
                const int t = (col >> 2) & 255;
                const float cf = b2f(Zb[(size_t)node * 512 + 256 + t]);
                const float c2 = sigm(gv[1]) * cf + sigm(gv[0]) * tanhf(gv[2]);
                const float hv = sigm(gv[3]) * tanhf(c2);
                H[(size_t)node * 256 + t] = f2b(hv);
                C[(size_t)node * 256 + t] = f2b(c2);
            }
        }
    }
}

// ---------------------------------------------------------------------------
// Fused Y-GEMM + NLL (levels 6..16). Block = 16 nodes, chunk-local j.
// ---------------------------------------------------------------------------
__global__ __launch_bounds__(256) void ynll(
    const ushort* __restrict__ Hb, const ushort* __restrict__ Cc,
    const ushort* __restrict__ Wyp,
    const float* __restrict__ fc_b, const float* __restrict__ X,
    ushort* __restrict__ FeatNext, float* __restrict__ loss,
    int Bc, long long nb_fi, float scale, int writeFeat)
{
    __shared__ ushort Hs[32 * 128];
    __shared__ float Ys[32][324];
    __shared__ float lsum[4];
    const int tid = threadIdx.x;
    const int lane = tid & 63;
    const int wv = tid >> 6;
    const int fr = lane & 15, fq = lane >> 4;
    const int n16 = blockIdx.x * 16;

    #pragma unroll
    for (int it = 0; it < 2; ++it) {
        const int i = it * 256 + tid;
        const int row = i >> 4, slot = i & 15;
        const int sl = slot ^ (row & 7);
        int gr = n16 * 2 + row;
        const int grmax = 2 * Bc - 1;
        gr = gr <= grmax ? gr : grmax;
        gload16(Hb + (size_t)gr * 128 + sl * 8, &Hs[(i - lane) * 8]);
    }
    __syncthreads();

    f32x4 acc[2][5] = {};
    #pragma unroll
    for (int ks = 0; ks < 4; ++ks) {
        short8 a[2];
        #pragma unroll
        for (int rf = 0; rf < 2; ++rf) {
            const int row = rf * 16 + fr;
            const int sl = (ks * 4 + fq) ^ (row & 7);
            a[rf] = *(const short8*)&Hs[row * 128 + sl * 8];
        }
        #pragma unroll
        for (int n = 0; n < 5; ++n) {
            const short8 b = *(const short8*)(
                Wyp + (size_t)(wv * 80 + n * 16 + fr) * 128 + ks * 32 + fq * 8);
            acc[0][n] = mfma16(a[0], b, acc[0][n]);
            acc[1][n] = mfma16(a[1], b, acc[1][n]);
        }
    }
    #pragma unroll
    for (int rf = 0; rf < 2; ++rf)
        #pragma unroll
        for (int n = 0; n < 5; ++n)
            #pragma unroll
            for (int j = 0; j < 4; ++j) {
                const int row = rf * 16 + fq * 4 + j;
                const int col = wv * 80 + n * 16 + fr;
                Ys[row][col] = acc[rf][n][j] + (col < 263 ? fc_b[col] : 0.f);
            }
    __syncthreads();

    float wsum = 0.f;
    #pragma unroll
    for (int s4 = 0; s4 < 4; ++s4) {
        const int jj = wv * 4 + s4;
        const int j = n16 + jj;
        if (j >= Bc) break;
        bool sw;
        wsum += nll_node(Ys[2 * jj + (lane >> 5)], X, nb_fi + j, lane, sw);
        if (writeFeat)
            feat_write(FeatNext, Hb + (size_t)j * 256, Cc + (size_t)j * 256,
                       j, sw, lane);
    }
    if (lane == 0) lsum[wv] = wsum;
    __syncthreads();
    if (tid == 0)
        atomicAdd(loss, (lsum[0] + lsum[1] + lsum[2] + lsum[3]) * scale);
}

// ---------------------------------------------------------------------------
// One-time repack, single launch.
// ---------------------------------------------------------------------------
__global__ __launch_bounds__(256) void pack_all(
    const float* __restrict__ fc_h_W, ushort* __restrict__ Wz,
    const float* __restrict__ Wih, const float* __restrict__ Whh,
    ushort* __restrict__ Wg,
    const float* __restrict__ bih, const float* __restrict__ bhh,
    float* __restrict__ bg,
    const float* __restrict__ fcW, ushort* __restrict__ Wy,
    const float* __restrict__ X, ushort* __restrict__ Xb, int nx)
{
    int i = blockIdx.x * 256 + threadIdx.x;
    if (i < 131072) { Wz[i] = f2b(fc_h_W[i]); return; }
    i -= 131072;
    if (i < 589824) {
        int np = i / 576, c = i - np * 576;
        int n = (np & 3) * 256 + (np >> 2);
        float v = 0.f;
        if (c < 264) v = Wih[n * 264 + c];
        else if (c < 520) v = Whh[n * 256 + (c - 264)];
        Wg[i] = f2b(v);
        return;
    }
    i -= 589824;
    if (i < 1024) {
        int n = (i & 3) * 256 + (i >> 2);
        bg[i] = bih[n] + bhh[n];
        return;
    }
    i -= 1024;
    if (i < 40960) {
        int r = i / 128;
        Wy[i] = f2b(r < 263 ? fcW[i] : 0.f);
        return;
    }
    i -= 40960;
    if (i < nx) Xb[i] = f2b(X[i]);
}

// ---------------------------------------------------------------------------
// Encoder: only the root feature matters. One block.
// ---------------------------------------------------------------------------
__global__ __launch_bounds__(256) void encoder_root(
    const float* __restrict__ X, const float* __restrict__ Feature,
    const float* __restrict__ Wih, const float* __restrict__ Whh,
    const float* __restrict__ bih, const float* __restrict__ bhh,
    ushort* __restrict__ Fcur0)
{
    __shared__ float gsh[2][512];
    __shared__ float hc[2][256];
    const int t = threadIdx.x;
    for (int ch = 0; ch < 2; ++ch) {
        const int node = 1 + ch;
        const float* x = X + node * 8;
        const float* h = Feature + (size_t)node * 256;
        #pragma unroll
        for (int gi = 0; gi < 2; ++gi) {
            int g = t + gi * 256;
            float s = bih[g] + bhh[g];
            const float* wi = Wih + (size_t)g * 8;
            #pragma unroll
            for (int k = 0; k < 8; ++k) s += wi[k] * x[k];
            const float* wh = Whh + (size_t)g * 128;
            for (int k = 0; k < 128; ++k) s += wh[k] * h[k];
            gsh[ch][g] = s;
        }
    }
    __syncthreads();
    {
        int ch = t >> 7, u = t & 127;
        float i_ = gsh[ch][u], f_ = gsh[ch][128 + u];
        float gg = gsh[ch][256 + u], o_ = gsh[ch][384 + u];
        float c = Feature[(size_t)(1 + ch) * 256 + 128 + u];
        float c2 = sigm(f_) * c + sigm(i_) * tanhf(gg);
        hc[ch][u] = sigm(o_) * tanhf(c2);
        hc[ch][128 + u] = c2;
    }
    __syncthreads();
    Fcur0[t] = f2b(hc[0][t] + hc[1][t]);
}

// ---------------------------------------------------------------------------
// small_levels: levels 0..5 (B<=32) fused in ONE regular single-block launch.
// Same phase A-D structure as the (failed) coop kernel but __syncthreads only
// -> isolates the phase logic from the cooperative-launch mechanism.
// ---------------------------------------------------------------------------
__global__ __launch_bounds__(256) void small_levels(
    const float* __restrict__ X, const ushort* __restrict__ Xb,
    ushort* __restrict__ featA, ushort* __restrict__ featB,
    const ushort* __restrict__ Wz, const float* __restrict__ fc_h_b,
    const ushort* __restrict__ Wg, const float* __restrict__ bg,
    const ushort* __restrict__ Wyp, const float* __restrict__ fc_b,
    ushort* __restrict__ Hb, ushort* __restrict__ Cc,
    float* __restrict__ loss)
{
    __shared__ char pool[53248] __attribute__((aligned(16)));
    __shared__ float lsum[4];
    ushort* Asm = (ushort*)pool;              // [32][576], slot XOR swizzle
    ushort* Zc  = (ushort*)(pool + 36864);    // [32][256] plain (c_f)
    ushort* Hs  = (ushort*)pool;              // phase D overlay: [32][128] swz
    float (*Ys)[324] = (float (*)[324])(pool + 8192);

    const int tid = threadIdx.x;
    const int lane = tid & 63;
    const int wv  = tid >> 6;
    const int fr = lane & 15, fq = lane >> 4;

    for (int l = 0; l <= 5; ++l) {
        const int B = 1 << l;
        const long long nb = B - 1;
        ushort* Fcur  = (l & 1) ? featB : featA;
        ushort* Fnext = (l & 1) ? featA : featB;
        const float scale = 1.f / ((float)B * 17.f);

        // ---- phase A: stage A = [X | F | (Zh later) | 0] for rows 0..31 ----
        for (int c = tid; c < 1280; c += 256) {
            const int r = c / 40, s5 = c - r * 40;
            const int s = s5 < 33 ? s5 : s5 + 32;
            const int ss = s ^ (r & 7);
            short8 v = {0, 0, 0, 0, 0, 0, 0, 0};
            if (s == 0)
                v = *(const short8*)(Xb + (size_t)(nb + r) * 8);
            else if (s < 33)
                v = *(const short8*)(Fcur + (size_t)r * 256 + (s - 1) * 8);
            *(short8*)&Asm[r * 576 + ss * 8] = v;
        }
        __syncthreads();
        // ---- phase B: Z = tanh(F @ Wz^T + b); wave wv -> cols 128wv.. ----
        {
            f32x4 acc[2][8] = {};
            for (int ks = 0; ks < 8; ++ks) {
                short8 a[2];
                #pragma unroll
                for (int mf = 0; mf < 2; ++mf) {
                    const int r = mf * 16 + fr;
                    const int ss = (1 + ks * 4 + fq) ^ (r & 7);
                    a[mf] = *(const short8*)&Asm[r * 576 + ss * 8];
                }
                #pragma unroll
                for (int nf = 0; nf < 8; ++nf) {
                    const short8 b = *(const short8*)(
                        Wz + (size_t)(wv * 128 + nf * 16 + fr) * 256 + ks * 32 + fq * 8);
                    acc[0][nf] = mfma16(a[0], b, acc[0][nf]);
                    acc[1][nf] = mfma16(a[1], b, acc[1][nf]);
                }
            }
            #pragma unroll
            for (int mf = 0; mf < 2; ++mf)
                #pragma unroll
                for (int nf = 0; nf < 8; ++nf)
                    #pragma unroll
                    for (int j = 0; j < 4; ++j) {
                        const int r = mf * 16 + fq * 4 + j;
                        const int col = wv * 128 + nf * 16 + fr;
                        const float z = tanhf(acc[mf][nf][j] + fc_h_b[col]);
                        if (col < 256) {
                            const int ss = (33 + (col >> 3)) ^ (r & 7);
                            Asm[r * 576 + ss * 8 + (col & 7)] = f2b(z);
                        } else {
                            Zc[r * 256 + (col - 256)] = f2b(z);
                        }
                    }
        }
        __syncthreads();
        // ---- phase C: gates + LSTM; wave wv -> cols 256wv.., 2 passes ----
        for (int p = 0; p < 2; ++p) {
            f32x4 acc[2][8] = {};
            const int cbase = wv * 256 + p * 128;
            for (int ks = 0; ks < 18; ++ks) {
                short8 a[2];
                #pragma unroll
                for (int mf = 0; mf < 2; ++mf) {
                    const int r = mf * 16 + fr;
                    const int ss = (ks * 4 + fq) ^ (r & 7);
                    a[mf] = *(const short8*)&Asm[r * 576 + ss * 8];
                }
                #pragma unroll
                for (int nf = 0; nf < 8; ++nf) {
                    const short8 b = *(const short8*)(
                        Wg + (size_t)(cbase + nf * 16 + fr) * 576 + ks * 32 + fq * 8);
                    acc[0][nf] = mfma16(a[0], b, acc[0][nf]);
                    acc[1][nf] = mfma16(a[1], b, acc[1][nf]);
                }
            }
            const int q = fr & 3;
            #pragma unroll
            for (int mf = 0; mf < 2; ++mf) {
                const int r = mf * 16 + fq * 4 + q;
                #pragma unroll
                for (int nf = 0; nf < 8; ++nf) {
                    const int col = cbase + nf * 16 + fr;
                    f32x4 v = acc[mf][nf];
                    const float bb = bg[col];
                    v[0] += bb; v[1] += bb; v[2] += bb; v[3] += bb;
                    float gv[4];
                    gv[q] = v[q];
                    #pragma unroll
                    for (int m = 1; m < 4; ++m)
                        gv[q ^ m] = __shfl_xor(v[q ^ m], m);
                    if (r < B) {
                        const int t = col >> 2;
                        const float cf = b2f(Zc[r * 256 + t]);
                        const float c2 = sigm(gv[1]) * cf + sigm(gv[0]) * tanhf(gv[2]);
                        const float hv = sigm(gv[3]) * tanhf(c2);
                        Hb[(size_t)r * 256 + t] = f2b(hv);
                        Cc[(size_t)r * 256 + t] = f2b(c2);
                    }
                }
            }
        }
        __syncthreads();
        // ---- phase D: Y + NLL + swap + child features, 2 x 16 nodes ----
        for (int sub = 0; sub < 2; ++sub) {
            const int n16 = sub * 16;
            if (n16 < B) {
                #pragma unroll
                for (int it = 0; it < 2; ++it) {
                    const int i = it * 256 + tid;
                    const int row = i >> 4, slot = i & 15;
                    const int sl = slot ^ (row & 7);
                    int gr = n16 * 2 + row;
                    const int grmax = 2 * B - 1;
                    gr = gr <= grmax ? gr : grmax;
                    gload16(Hb + (size_t)gr * 128 + sl * 8, &Hs[(i - lane) * 8]);
                }
                __syncthreads();
                f32x4 acc[2][5] = {};
                #pragma unroll
                for (int ks = 0; ks < 4; ++ks) {
                    short8 a[2];
                    #pragma unroll
                    for (int rf = 0; rf < 2; ++rf) {
                        const int row = rf * 16 + fr;
                        const int sl = (ks * 4 + fq) ^ (row & 7);
                        a[rf] = *(const short8*)&Hs[row * 128 + sl * 8];
                    }
                    #pragma unroll
                    for (int n = 0; n < 5; ++n) {
                        const short8 b = *(const short8*)(
                            Wyp + (size_t)(wv * 80 + n * 16 + fr) * 128 + ks * 32 + fq * 8);
                        acc[0][n] = mfma16(a[0], b, acc[0][n]);
                        acc[1][n] = mfma16(a[1], b, acc[1][n]);
                    }
                }
                #pragma unroll
                for (int rf = 0; rf < 2; ++rf)
                    #pragma unroll
                    for (int n = 0; n < 5; ++n)
                        #pragma unroll
                        for (int j = 0; j < 4; ++j) {
                            const int row = rf * 16 + fq * 4 + j;
                            const int col = wv * 80 + n * 16 + fr;
                            Ys[row][col] = acc[rf][n][j] + (col < 263 ? fc_b[col] : 0.f);
                        }
                __syncthreads();
                float wsum = 0.f;
                #pragma unroll
                for (int s4 = 0; s4 < 4; ++s4) {
                    const int jj = wv * 4 + s4;
                    const int j = n16 + jj;
                    if (j >= B) break;
                    bool sw;
                    wsum += nll_node(Ys[2 * jj + (lane >> 5)], X, nb + j, lane, sw);
                    feat_write(Fnext, Hb + (size_t)j * 256, Cc + (size_t)j * 256,
                               j, sw, lane);
                }
                if (lane == 0) lsum[wv] = wsum;
                __syncthreads();
                if (tid == 0)
                    atomicAdd(loss, (lsum[0] + lsum[1] + lsum[2] + lsum[3]) * scale);
                __syncthreads();
            }
        }
    }
}

// ---------------------------------------------------------------------------
extern "C" void kernel_launch(void* const* d_in, const int* in_sizes, int n_in,
                              void* d_out, int out_size, void* d_ws, size_t ws_size,
                              hipStream_t stream)
{
    const float* X       = (const float*)d_in[0];
    const float* Feature = (const float*)d_in[1];
    const float* W_ih_e  = (const float*)d_in[3];
    const float* W_hh_e  = (const float*)d_in[4];
    const float* b_ih_e  = (const float*)d_in[5];
    const float* b_hh_e  = (const float*)d_in[6];
    const float* fc_h_W  = (const float*)d_in[7];
    const float* fc_h_b  = (const float*)d_in[8];
    const float* W_ih_d  = (const float*)d_in[9];
    const float* W_hh_d  = (const float*)d_in[10];
    const float* b_ih_d  = (const float*)d_in[11];
    const float* b_hh_d  = (const float*)d_in[12];
    const float* fc_W    = (const float*)d_in[13];
    const float* fc_b    = (const float*)d_in[14];
    const int Nnodes = in_sizes[0] / 8;   // 262143

    float* out = (float*)d_out;
    hipMemsetAsync(d_out, 0, sizeof(float), stream);

    char* cur = (char*)d_ws;
    auto take = [&](size_t bytes) {
        char* p = cur;
        cur += (bytes + 255) & ~(size_t)255;
        return p;
    };
    ushort* featA = (ushort*)take((size_t)65536 * 256 * 2);
    ushort* featB = (ushort*)take((size_t)32768 * 256 * 2);
    ushort* Wz    = (ushort*)take((size_t)512 * 256 * 2);
    ushort* Wg    = (ushort*)take((size_t)1024 * 576 * 2);
    ushort* Wy    = (ushort*)take((size_t)320 * 128 * 2);
    float*  bg    = (float*) take((size_t)1024 * 4);
    ushort* Xb    = (ushort*)take((size_t)Nnodes * 8 * 2);
    const size_t fixed_used = (size_t)(cur - (char*)d_ws);
    int CB = 65536;
    while (CB > 8192 && fixed_used + (size_t)CB * 2048 + 4096 > ws_size) CB >>= 1;
    ushort* Zb = (ushort*)take((size_t)CB * 512 * 2);
    ushort* Hb = (ushort*)take((size_t)CB * 256 * 2);
    ushort* Cc = (ushort*)take((size_t)CB * 256 * 2);

    const int nx = Nnodes * 8;
    const int packTotal = 131072 + 589824 + 1024 + 40960 + nx;
    pack_all<<<(packTotal + 255) / 256, 256, 0, stream>>>(
        fc_h_W, Wz, W_ih_d, W_hh_d, Wg, b_ih_d, b_hh_d, bg, fc_W, Wy, X, Xb, nx);

    encoder_root<<<1, 256, 0, stream>>>(X, Feature, W_ih_e, W_hh_e, b_ih_e, b_hh_e, featA);

    // levels 0..5: single-block fused kernel (regular launch)
    small_levels<<<1, 256, 0, stream>>>(
        X, Xb, featA, featB, Wz, fc_h_b, Wg, bg, Wy, fc_b, Hb, Cc, out);

    // levels 6..16: 3-kernel pipeline
    for (int l = 6; l < 17; ++l) {
        const int B = 1 << l;
        const long long nb = B - 1;
        ushort* Fcur  = (l & 1) ? featB : featA;
        ushort* Fnext = (l & 1) ? featA : featB;
        const int writeFeat = (l < 16) ? 1 : 0;
        const float scale = 1.f / ((float)B * 17.f);
        for (int j0 = 0; j0 < B; j0 += CB) {
            const int Bc = (B - j0 < CB) ? (B - j0) : CB;
            const int mg = (Bc + 127) / 128;
            gemm_bf16<1, 1, 256><<<dim3(mg, 4), 256, 0, stream>>>(
                Fcur + (size_t)j0 * 256, 256, Bc - 1,
                Wz, 256, 511,
                fc_h_b, nullptr, Zb, 512, Bc, 512);
            gates_lstm<<<dim3(mg, 8), 256, 0, stream>>>(
                Xb + (size_t)(nb + j0) * 8,
                Fcur + (size_t)j0 * 256,
                Zb, Wg, bg, Hb, Cc, Bc);
            ynll<<<(Bc + 15) / 16, 256, 0, stream>>>(
                Hb, Cc, Wy, fc_b, X,
                (writeFeat ? Fnext + (size_t)2 * j0 * 256 : (ushort*)nullptr), out,
                Bc, nb + j0, scale, writeFeat);
        }
    }
}

// Round 7
// 1601.004 us; speedup vs baseline: 1.1103x; 1.1103x over previous
//
#include <hip/hip_runtime.h>
#include <hip/hip_bf16.h>
#include <math.h>

// ---------------------------------------------------------------------------
// D=256, LVL=17, MIX=20. N nodes = 2^18-1; internal = 2^17-1 = 131071.
//  * Encoder reads ORIGINAL Feature -> only root's encoded feature survives.
//  * Decoder: 17 sequential levels; level l has B=2^l nodes. X_P dead.
// R7: levels 0..10 in ONE 64-block kernel with manual grid barriers
//     (atomic counter + fences; 2 barriers/level; Z computed redundantly
//     per block to avoid a third). Levels 11..16: proven 3-kernel pipeline.
// ---------------------------------------------------------------------------

#define LOG2PI 1.8378770664093453f
#define NBLK 64

typedef __attribute__((ext_vector_type(8))) short short8;
typedef __attribute__((ext_vector_type(4))) float f32x4;

__device__ inline float sigm(float x) { return 1.0f / (1.0f + expf(-x)); }

__device__ inline ushort f2b(float v) {
    union { float f; unsigned u; } x; x.f = v;
    unsigned r = x.u + 0x7fffu + ((x.u >> 16) & 1u);
    return (ushort)(r >> 16);
}
__device__ inline float b2f(ushort h) {
    union { unsigned u; float f; } x; x.u = ((unsigned)h) << 16; return x.f;
}

__device__ inline void gload16(const void* g, void* l) {
    __builtin_amdgcn_global_load_lds(
        (const __attribute__((address_space(1))) unsigned*)g,
        (__attribute__((address_space(3))) unsigned*)l, 16, 0, 0);
}

__device__ inline f32x4 mfma16(short8 a, short8 b, f32x4 c) {
    return __builtin_amdgcn_mfma_f32_16x16x32_bf16(a, b, c, 0, 0, 0);
}

// Device-scope grid barrier (all NBLK blocks co-resident). Counter zeroed
// per kernel_launch via hipMemsetAsync. Monotonic-counter barrier.
__device__ inline void gridbar(unsigned* cnt) {
    __syncthreads();
    if (threadIdx.x == 0) {
        __threadfence();
        unsigned old = atomicAdd(cnt, 1u);
        unsigned target = (old / (unsigned)NBLK + 1u) * (unsigned)NBLK;
        long long guard = 0;
        while (guard < 400000000LL) {
            unsigned v = __hip_atomic_load(cnt, __ATOMIC_ACQUIRE,
                                           __HIP_MEMORY_SCOPE_AGENT);
            if (v >= target) break;
            __builtin_amdgcn_s_sleep(2);
            ++guard;
        }
        __threadfence();
    }
    __syncthreads();
}

__device__ inline float halfmax(float v) {
    #pragma unroll
    for (int o = 16; o >= 1; o >>= 1) v = fmaxf(v, __shfl_xor(v, o));
    return v;
}
__device__ inline float halfsum(float v) {
    #pragma unroll
    for (int o = 16; o >= 1; o >>= 1) v += __shfl_xor(v, o);
    return v;
}
__device__ inline float lse20(float t) {
    float m = halfmax(t);
    float s = halfsum(expf(t - m));
    return m + logf(s);
}

// NLL for one node; yb = this half's 263-float Y row. Wave-collective.
__device__ inline float nll_node(const float* yb, const float* X,
                                 long long fi, int lane, bool& sw_out)
{
    const int half = lane >> 5, k = lane & 31;
    float v = (k < 20) ? yb[k] : -INFINITY;
    float mm = halfmax(v);
    float se = halfsum((k < 20) ? expf(v - mm) : 0.f);
    float lpi = v - mm - logf(se);
    float mx = 0, my = 0, sx = 1, sy = 1, rho = 0, omr = 1, cxy = 0;
    float ma = 0, mb2 = 0, sa = 1, sb = 1, rab = 0, omr2 = 1, cab = 0;
    float ms = 0, ss2 = 1, csl = 0;
    if (k < 20) {
        mx = yb[20 + k]; my = yb[40 + k];
        float lsx = yb[60 + k], lsy = yb[80 + k];
        sx = expf(lsx); sy = expf(lsy);
        rho = tanhf(yb[100 + k]); omr = 1.f - rho * rho;
        cxy = LOG2PI + lsx + lsy + 0.5f * logf(omr);
        ma = yb[120 + k]; mb2 = yb[140 + k];
        float lsa = yb[160 + k], lsb = yb[180 + k];
        sa = expf(lsa); sb = expf(lsb);
        rab = tanhf(yb[200 + k]); omr2 = 1.f - rab * rab;
        cab = LOG2PI + lsa + lsb + 0.5f * logf(omr2);
        ms = yb[220 + k]; float lss = yb[240 + k];
        ss2 = expf(lss);
        csl = 0.5f * LOG2PI + lss;
    }
    float lq0, lq1, lq2;
    {
        float q0 = yb[260], q1 = yb[261], q2 = yb[262];
        float qm = fmaxf(q0, fmaxf(q1, q2));
        float l = logf(expf(q0 - qm) + expf(q1 - qm) + expf(q2 - qm)) + qm;
        lq0 = q0 - l; lq1 = q1 - l; lq2 = q2 - l;
    }
    const float* pl = X + (size_t)(2 * fi + 1) * 8;
    const float* pr = X + (size_t)(2 * fi + 2) * 8;
    float res[2];
    #pragma unroll
    for (int s = 0; s < 2; ++s) {
        const float* pt = s ? pr : pl;
        float dx = pt[0], dy = pt[1], da = pt[2], db = pt[3], ds = pt[4];
        float t1 = -INFINITY, t2 = -INFINITY, t3 = -INFINITY;
        if (k < 20) {
            float zx = (dx - mx) / sx, zy = (dy - my) / sy;
            float Zz = zx * zx + zy * zy - 2.f * rho * zx * zy;
            t1 = lpi - Zz / (2.f * omr) - cxy;
            float za = (da - ma) / sa, zb = (db - mb2) / sb;
            float Z2 = za * za + zb * zb - 2.f * rab * za * zb;
            t2 = lpi - Z2 / (2.f * omr2) - cab;
            float zs = ds - ms;
            t3 = lpi - (zs * zs) / (2.f * ss2 * ss2) - csl;
        }
        float l1 = lse20(t1), l2 = lse20(t2), l3 = lse20(t3);
        float pen = -(pt[5] * lq0 + pt[6] * lq1 + pt[7] * lq2);
        res[s] = -(l1 + l2 + l3) + pen;
    }
    float Aval = half ? res[1] : res[0];
    float Bval = half ? res[0] : res[1];
    float direct = Aval + __shfl_xor(Aval, 32);
    float swapped = Bval + __shfl_xor(Bval, 32);
    sw_out = swapped < direct;
    return sw_out ? swapped : direct;
}

__device__ inline void feat_write(ushort* FeatNext, const ushort* Hj,
                                  const ushort* Cj, long long j, bool sw, int lane)
{
    const size_t Jg = 2 * (size_t)j;
    const int offL = sw ? 128 : 0;
    const int offR = 128 - offL;
    const int part = lane >> 5;
    const int c = (lane & 31) * 4;
    ushort4 vL = *(const ushort4*)((part ? Cj : Hj) + offL + c);
    ushort4 vR = *(const ushort4*)((part ? Cj : Hj) + offR + c);
    *(ushort4*)(FeatNext + Jg * 256 + part * 128 + c) = vL;
    *(ushort4*)(FeatNext + (Jg + 1) * 256 + part * 128 + c) = vR;
}

// ---------------------------------------------------------------------------
// bf16 NT GEMM (Z): C = tanh(A @ B^T + bias) -> bf16. K templated+unrolled.
// ---------------------------------------------------------------------------
template <int ACT, int OUT_MODE, int KK>
__global__ __launch_bounds__(256) void gemm_bf16(
    const ushort* __restrict__ A, int lda, int Mclamp,
    const ushort* __restrict__ B, int ldb, int Nclamp,
    const float* __restrict__ bias0,
    float* __restrict__ Cf, ushort* __restrict__ Cb, int ldc,
    int M, int N)
{
    __shared__ ushort As[128 * 64];
    __shared__ ushort Bs[128 * 64];
    const int tid = threadIdx.x;
    const int lane = tid & 63;
    const int w = tid >> 6;
    const int wr = w >> 1, wc = w & 1;
    const int fr = lane & 15, fq = lane >> 4;
    const int m0 = blockIdx.x * 128, n0 = blockIdx.y * 128;

    f32x4 acc[4][4] = {};

    #pragma unroll
    for (int k0 = 0; k0 < KK; k0 += 64) {
        __syncthreads();
        #pragma unroll
        for (int it = 0; it < 4; ++it) {
            const int i = it * 256 + tid;
            const int row = i >> 3, slot = i & 7;
            const int sl = slot ^ (row & 7);
            const int wbase = (i - lane) * 8;
            {
                int gm = m0 + row; gm = gm <= Mclamp ? gm : Mclamp;
                gload16(A + (size_t)gm * lda + k0 + sl * 8, &As[wbase]);
            }
            {
                int gn = n0 + row; gn = gn <= Nclamp ? gn : Nclamp;
                gload16(B + (size_t)gn * ldb + k0 + sl * 8, &Bs[wbase]);
            }
        }
        __syncthreads();
        #pragma unroll
        for (int ks = 0; ks < 2; ++ks) {
            short8 af[4], bfr[4];
            #pragma unroll
            for (int mr = 0; mr < 4; ++mr) {
                const int row = wr * 64 + mr * 16 + fr;
                const int sl = (ks * 4 + fq) ^ (row & 7);
                af[mr] = *(const short8*)&As[row * 64 + sl * 8];
            }
            #pragma unroll
            for (int nc = 0; nc < 4; ++nc) {
                const int row = wc * 64 + nc * 16 + fr;
                const int sl = (ks * 4 + fq) ^ (row & 7);
                bfr[nc] = *(const short8*)&Bs[row * 64 + sl * 8];
            }
            #pragma unroll
            for (int mr = 0; mr < 4; ++mr)
                #pragma unroll
                for (int nc = 0; nc < 4; ++nc)
                    acc[mr][nc] = mfma16(af[mr], bfr[nc], acc[mr][nc]);
        }
    }

    #pragma unroll
    for (int mr = 0; mr < 4; ++mr) {
        #pragma unroll
        for (int j = 0; j < 4; ++j) {
            const int row = m0 + wr * 64 + mr * 16 + fq * 4 + j;
            if (row >= M) continue;
            #pragma unroll
            for (int nc = 0; nc < 4; ++nc) {
                const int col = n0 + wc * 64 + nc * 16 + fr;
                if (col >= N) continue;
                float v = acc[mr][nc][j] + bias0[col];
                if (ACT == 1) v = tanhf(v);
                if (OUT_MODE == 0) Cf[(size_t)row * ldc + col] = v;
                else               Cb[(size_t)row * ldc + col] = f2b(v);
            }
        }
    }
}

// ---------------------------------------------------------------------------
// Fused gates GEMM + LSTM epilogue (levels 11..16). k0 fully unrolled.
// ---------------------------------------------------------------------------
__global__ __launch_bounds__(256) void gates_lstm(
    const ushort* __restrict__ Xb,
    const ushort* __restrict__ Fcur,
    const ushort* __restrict__ Zb,
    const ushort* __restrict__ Wg,
    const float*  __restrict__ bg,
    ushort* __restrict__ H, ushort* __restrict__ C, int M)
{
    __shared__ ushort As[128 * 64];
    __shared__ ushort Bs[128 * 64];
    const int tid = threadIdx.x;
    const int lane = tid & 63;
    const int w = tid >> 6;
    const int wr = w >> 1, wc = w & 1;
    const int fr = lane & 15, fq = lane >> 4;
    const int m0 = blockIdx.x * 128, n0 = blockIdx.y * 128;

    f32x4 acc[4][4] = {};

    #pragma unroll
    for (int k0 = 0; k0 < 576; k0 += 64) {
        __syncthreads();
        const int sbase = k0 >> 3;
        #pragma unroll
        for (int it = 0; it < 4; ++it) {
            const int i = it * 256 + tid;
            const int row = i >> 3, slot = i & 7;
            const int sl = slot ^ (row & 7);
            const int wbase = (i - lane) * 8;
            {
                int gm = m0 + row; gm = gm < M ? gm : M - 1;
                const int a = sbase + sl;
                const ushort* src;
                if (a == 0)      src = Xb   + (size_t)gm * 8;
                else if (a < 33) src = Fcur + (size_t)gm * 256 + (size_t)(a - 1) * 8;
                else if (a < 65) src = Zb   + (size_t)gm * 512 + (size_t)(a - 33) * 8;
                else             src = Zb   + (size_t)gm * 512;   // junk; Wg cols zero
                gload16(src, &As[wbase]);
            }
            gload16(Wg + (size_t)(n0 + row) * 576 + k0 + sl * 8, &Bs[wbase]);
        }
        __syncthreads();
        #pragma unroll
        for (int ks = 0; ks < 2; ++ks) {
            short8 af[4], bfr[4];
            #pragma unroll
            for (int mr = 0; mr < 4; ++mr) {
                const int row = wr * 64 + mr * 16 + fr;
                const int sl = (ks * 4 + fq) ^ (row & 7);
                af[mr] = *(const short8*)&As[row * 64 + sl * 8];
            }
            #pragma unroll
            for (int nc = 0; nc < 4; ++nc) {
                const int row = wc * 64 + nc * 16 + fr;
                const int sl = (ks * 4 + fq) ^ (row & 7);
                bfr[nc] = *(const short8*)&Bs[row * 64 + sl * 8];
            }
            #pragma unroll
            for (int mr = 0; mr < 4; ++mr)
                #pragma unroll
                for (int nc = 0; nc < 4; ++nc)
                    acc[mr][nc] = mfma16(af[mr], bfr[nc], acc[mr][nc]);
        }
    }

    const int q = fr & 3;
    #pragma unroll
    for (int mr = 0; mr < 4; ++mr) {
        const int node = m0 + wr * 64 + mr * 16 + fq * 4 + q;
        #pragma unroll
        for (int nc = 0; nc < 4; ++nc) {
            const int col = n0 + wc * 64 + nc * 16 + fr;
            f32x4 v = acc[mr][nc];
            const float b = bg[col];
            v[0] += b; v[1] += b; v[2] += b; v[3] += b;
            float gv[4];
            gv[q] = v[q];
            #pragma unroll
            for (int m = 1; m < 4; ++m)
                gv[q ^ m] = __shfl_xor(v[q ^ m], m);
            if (node < M) {
                const int t = (col >> 2) & 255;
                const float cf = b2f(Zb[(size_t)node * 512 + 256 + t]);
                const float c2 = sigm(gv[1]) * cf + sigm(gv[0]) * tanhf(gv[2]);
                const float hv = sigm(gv[3]) * tanhf(c2);
                H[(size_t)node * 256 + t] = f2b(hv);
                C[(size_t)node * 256 + t] = f2b(c2);
            }
        }
    }
}

// ---------------------------------------------------------------------------
// Fused Y-GEMM + NLL (levels 11..16). Block = 16 nodes, chunk-local j.
// ---------------------------------------------------------------------------
__global__ __launch_bounds__(256) void ynll(
    const ushort* __restrict__ Hb, const ushort* __restrict__ Cc,
    const ushort* __restrict__ Wyp,
    const float* __restrict__ fc_b, const float* __restrict__ X,
    ushort* __restrict__ FeatNext, float* __restrict__ loss,
    int Bc, long long nb_fi, float scale, int writeFeat)
{
    __shared__ ushort Hs[32 * 128];
    __shared__ float Ys[32][324];
    __shared__ float lsum[4];
    const int tid = threadIdx.x;
    const int lane = tid & 63;
    const int wv = tid >> 6;
    const int fr = lane & 15, fq = lane >> 4;
    const int n16 = blockIdx.x * 16;

    #pragma unroll
    for (int it = 0; it < 2; ++it) {
        const int i = it * 256 + tid;
        const int row = i >> 4, slot = i & 15;
        const int sl = slot ^ (row & 7);
        int gr = n16 * 2 + row;
        const int grmax = 2 * Bc - 1;
        gr = gr <= grmax ? gr : grmax;
        gload16(Hb + (size_t)gr * 128 + sl * 8, &Hs[(i - lane) * 8]);
    }
    __syncthreads();

    f32x4 acc[2][5] = {};
    #pragma unroll
    for (int ks = 0; ks < 4; ++ks) {
        short8 a[2];
        #pragma unroll
        for (int rf = 0; rf < 2; ++rf) {
            const int row = rf * 16 + fr;
            const int sl = (ks * 4 + fq) ^ (row & 7);
            a[rf] = *(const short8*)&Hs[row * 128 + sl * 8];
        }
        #pragma unroll
        for (int n = 0; n < 5; ++n) {
            const short8 b = *(const short8*)(
                Wyp + (size_t)(wv * 80 + n * 16 + fr) * 128 + ks * 32 + fq * 8);
            acc[0][n] = mfma16(a[0], b, acc[0][n]);
            acc[1][n] = mfma16(a[1], b, acc[1][n]);
        }
    }
    #pragma unroll
    for (int rf = 0; rf < 2; ++rf)
        #pragma unroll
        for (int n = 0; n < 5; ++n)
            #pragma unroll
            for (int j = 0; j < 4; ++j) {
                const int row = rf * 16 + fq * 4 + j;
                const int col = wv * 80 + n * 16 + fr;
                Ys[row][col] = acc[rf][n][j] + (col < 263 ? fc_b[col] : 0.f);
            }
    __syncthreads();

    float wsum = 0.f;
    #pragma unroll
    for (int s4 = 0; s4 < 4; ++s4) {
        const int jj = wv * 4 + s4;
        const int j = n16 + jj;
        if (j >= Bc) break;
        bool sw;
        wsum += nll_node(Ys[2 * jj + (lane >> 5)], X, nb_fi + j, lane, sw);
        if (writeFeat)
            feat_write(FeatNext, Hb + (size_t)j * 256, Cc + (size_t)j * 256,
                       j, sw, lane);
    }
    if (lane == 0) lsum[wv] = wsum;
    __syncthreads();
    if (tid == 0)
        atomicAdd(loss, (lsum[0] + lsum[1] + lsum[2] + lsum[3]) * scale);
}

// ---------------------------------------------------------------------------
// One-time repack, single launch.
// ---------------------------------------------------------------------------
__global__ __launch_bounds__(256) void pack_all(
    const float* __restrict__ fc_h_W, ushort* __restrict__ Wz,
    const float* __restrict__ Wih, const float* __restrict__ Whh,
    ushort* __restrict__ Wg,
    const float* __restrict__ bih, const float* __restrict__ bhh,
    float* __restrict__ bg,
    const float* __restrict__ fcW, ushort* __restrict__ Wy,
    const float* __restrict__ X, ushort* __restrict__ Xb, int nx)
{
    int i = blockIdx.x * 256 + threadIdx.x;
    if (i < 131072) { Wz[i] = f2b(fc_h_W[i]); return; }
    i -= 131072;
    if (i < 589824) {
        int np = i / 576, c = i - np * 576;
        int n = (np & 3) * 256 + (np >> 2);
        float v = 0.f;
        if (c < 264) v = Wih[n * 264 + c];
        else if (c < 520) v = Whh[n * 256 + (c - 264)];
        Wg[i] = f2b(v);
        return;
    }
    i -= 589824;
    if (i < 1024) {
        int n = (i & 3) * 256 + (i >> 2);
        bg[i] = bih[n] + bhh[n];
        return;
    }
    i -= 1024;
    if (i < 40960) {
        int r = i / 128;
        Wy[i] = f2b(r < 263 ? fcW[i] : 0.f);
        return;
    }
    i -= 40960;
    if (i < nx) Xb[i] = f2b(X[i]);
}

// ---------------------------------------------------------------------------
// Encoder: only the root feature matters. One block.
// ---------------------------------------------------------------------------
__global__ __launch_bounds__(256) void encoder_root(
    const float* __restrict__ X, const float* __restrict__ Feature,
    const float* __restrict__ Wih, const float* __restrict__ Whh,
    const float* __restrict__ bih, const float* __restrict__ bhh,
    ushort* __restrict__ Fcur0)
{
    __shared__ float gsh[2][512];
    __shared__ float hc[2][256];
    const int t = threadIdx.x;
    for (int ch = 0; ch < 2; ++ch) {
        const int node = 1 + ch;
        const float* x = X + node * 8;
        const float* h = Feature + (size_t)node * 256;
        #pragma unroll
        for (int gi = 0; gi < 2; ++gi) {
            int g = t + gi * 256;
            float s = bih[g] + bhh[g];
            const float* wi = Wih + (size_t)g * 8;
            #pragma unroll
            for (int k = 0; k < 8; ++k) s += wi[k] * x[k];
            const float* wh = Whh + (size_t)g * 128;
            for (int k = 0; k < 128; ++k) s += wh[k] * h[k];
            gsh[ch][g] = s;
        }
    }
    __syncthreads();
    {
        int ch = t >> 7, u = t & 127;
        float i_ = gsh[ch][u], f_ = gsh[ch][128 + u];
        float gg = gsh[ch][256 + u], o_ = gsh[ch][384 + u];
        float c = Feature[(size_t)(1 + ch) * 256 + 128 + u];
        float c2 = sigm(f_) * c + sigm(i_) * tanhf(gg);
        hc[ch][u] = sigm(o_) * tanhf(c2);
        hc[ch][128 + u] = c2;
    }
    __syncthreads();
    Fcur0[t] = f2b(hc[0][t] + hc[1][t]);
}

// ---------------------------------------------------------------------------
// fused_levels: levels 0..10 (B<=1024), NBLK=64 blocks, manual grid barriers.
// Per level: block = (group g = blk % ngroups, chunk = blk / ngroups).
//  Phase 1: stage [X|F] for group's 32 nodes; compute FULL Z locally
//           (redundant across chunks, kills a barrier); compute gate cols
//           [chunk*ncols, +ncols) + LSTM epilogue -> H,C global.  BARRIER.
//  Phase 2: 16-node tiles round-robin: Y-GEMM + NLL + feat write.  BARRIER.
// ---------------------------------------------------------------------------
__global__ __launch_bounds__(256) void fused_levels(
    const float* __restrict__ X, const ushort* __restrict__ Xb,
    ushort* __restrict__ featA, ushort* __restrict__ featB,
    const ushort* __restrict__ Wz, const float* __restrict__ fc_h_b,
    const ushort* __restrict__ Wg, const float* __restrict__ bg,
    const ushort* __restrict__ Wyp, const float* __restrict__ fc_b,
    ushort* __restrict__ Hb, ushort* __restrict__ Cc,
    float* __restrict__ loss, unsigned* __restrict__ barcnt)
{
    __shared__ char pool[53248] __attribute__((aligned(16)));
    __shared__ float lsum[4];
    ushort* Asm = (ushort*)pool;              // [32][576], slot XOR swizzle
    ushort* Zc  = (ushort*)(pool + 36864);    // [32][256] plain (c_f)
    ushort* Hs  = (ushort*)pool;              // phase 2 overlay: [32][128] swz
    float (*Ys)[324] = (float (*)[324])(pool + 8192);

    const int tid = threadIdx.x;
    const int lane = tid & 63;
    const int wv  = tid >> 6;
    const int fr = lane & 15, fq = lane >> 4;
    const int blk = blockIdx.x;

    for (int l = 0; l <= 10; ++l) {
        const int B = 1 << l;
        const long long nb = B - 1;
        ushort* Fcur  = (l & 1) ? featB : featA;
        ushort* Fnext = (l & 1) ? featA : featB;
        const float scale = 1.f / ((float)B * 17.f);
        const int ngroups = (B + 31) >> 5;          // pow2, <= 32
        const int nchunks = NBLK / ngroups;         // >= 2
        const int g = blk % ngroups;
        const int chunk = blk / ngroups;
        const int gbase = g * 32;
        const int ncols = 1024 / nchunks;           // gate cols per block
        const int ncf = ncols >> 4;                 // 16-col frags per block

        // ---- phase 1a: stage A = [X | F | (Zh later) | 0] for group rows ----
        for (int c = tid; c < 1280; c += 256) {
            const int r = c / 40, s5 = c - r * 40;
            const int s = s5 < 33 ? s5 : s5 + 32;
            const int ss = s ^ (r & 7);
            short8 v = {0, 0, 0, 0, 0, 0, 0, 0};
            int node = gbase + r; node = node < B ? node : B - 1;
            if (s == 0)
                v = *(const short8*)(Xb + (size_t)(nb + node) * 8);
            else if (s < 33)
                v = *(const short8*)(Fcur + (size_t)node * 256 + (s - 1) * 8);
            *(short8*)&Asm[r * 576 + ss * 8] = v;
        }
        __syncthreads();
        // ---- phase 1b: FULL Z = tanh(F @ Wz^T + b); wave wv -> 128 cols ----
        {
            f32x4 acc[2][8] = {};
            for (int ks = 0; ks < 8; ++ks) {
                short8 a[2];
                #pragma unroll
                for (int mf = 0; mf < 2; ++mf) {
                    const int r = mf * 16 + fr;
                    const int ss = (1 + ks * 4 + fq) ^ (r & 7);
                    a[mf] = *(const short8*)&Asm[r * 576 + ss * 8];
                }
                #pragma unroll
                for (int nf = 0; nf < 8; ++nf) {
                    const short8 b = *(const short8*)(
                        Wz + (size_t)(wv * 128 + nf * 16 + fr) * 256 + ks * 32 + fq * 8);
                    acc[0][nf] = mfma16(a[0], b, acc[0][nf]);
                    acc[1][nf] = mfma16(a[1], b, acc[1][nf]);
                }
            }
            #pragma unroll
            for (int mf = 0; mf < 2; ++mf)
                #pragma unroll
                for (int nf = 0; nf < 8; ++nf)
                    #pragma unroll
                    for (int j = 0; j < 4; ++j) {
                        const int r = mf * 16 + fq * 4 + j;
                        const int col = wv * 128 + nf * 16 + fr;
                        const float z = tanhf(acc[mf][nf][j] + fc_h_b[col]);
                        if (col < 256) {
                            const int ss = (33 + (col >> 3)) ^ (r & 7);
                            Asm[r * 576 + ss * 8 + (col & 7)] = f2b(z);
                        } else {
                            Zc[r * 256 + (col - 256)] = f2b(z);
                        }
                    }
        }
        __syncthreads();
        // ---- phase 1c: gates for col chunk + LSTM epilogue -> H,C global ----
        {
            const int col0c = chunk * ncols;
            for (int cf = wv; cf < ncf; cf += 4) {
                const int colf = col0c + cf * 16;
                f32x4 acc0 = {}, acc1 = {};
                for (int ks = 0; ks < 18; ++ks) {
                    short8 a0, a1;
                    {
                        const int r = fr;
                        const int ss = (ks * 4 + fq) ^ (r & 7);
                        a0 = *(const short8*)&Asm[r * 576 + ss * 8];
                    }
                    {
                        const int r = 16 + fr;
                        const int ss = (ks * 4 + fq) ^ (r & 7);
                        a1 = *(const short8*)&Asm[r * 576 + ss * 8];
                    }
                    const short8 b = *(const short8*)(
                        Wg + (size_t)(colf + fr) * 576 + ks * 32 + fq * 8);
                    acc0 = mfma16(a0, b, acc0);
                    acc1 = mfma16(a1, b, acc1);
                }
                const int q = fr & 3;
                const int col = colf + fr;
                const float bb = bg[col];
                const int t = col >> 2;
                #pragma unroll
                for (int rf = 0; rf < 2; ++rf) {
                    f32x4 v = rf ? acc1 : acc0;
                    v[0] += bb; v[1] += bb; v[2] += bb; v[3] += bb;
                    float gv[4];
                    gv[q] = v[q];
                    #pragma unroll
                    for (int m = 1; m < 4; ++m)
                        gv[q ^ m] = __shfl_xor(v[q ^ m], m);
                    const int node = gbase + rf * 16 + fq * 4 + q;
                    if (node < B) {
                        const float cf_ = b2f(Zc[(rf * 16 + fq * 4 + q) * 256 + t]);
                        const float c2 = sigm(gv[1]) * cf_ + sigm(gv[0]) * tanhf(gv[2]);
                        const float hv = sigm(gv[3]) * tanhf(c2);
                        Hb[(size_t)node * 256 + t] = f2b(hv);
                        Cc[(size_t)node * 256 + t] = f2b(c2);
                    }
                }
            }
        }
        gridbar(barcnt);
        // ---- phase 2: Y + NLL + swap + child features, 16-node tiles ----
        for (int t16 = blk; t16 * 16 < B; t16 += NBLK) {
            const int n16 = t16 * 16;
            #pragma unroll
            for (int it = 0; it < 2; ++it) {
                const int i = it * 256 + tid;
                const int row = i >> 4, slot = i & 15;
                const int sl = slot ^ (row & 7);
                int gr = n16 * 2 + row;
                const int grmax = 2 * B - 1;
                gr = gr <= grmax ? gr : grmax;
                gload16(Hb + (size_t)gr * 128 + sl * 8, &Hs[(i - lane) * 8]);
            }
            __syncthreads();
            f32x4 acc[2][5] = {};
            #pragma unroll
            for (int ks = 0; ks < 4; ++ks) {
                short8 a[2];
                #pragma unroll
                for (int rf = 0; rf < 2; ++rf) {
                    const int row = rf * 16 + fr;
                    const int sl = (ks * 4 + fq) ^ (row & 7);
                    a[rf] = *(const short8*)&Hs[row * 128 + sl * 8];
                }
                #pragma unroll
                for (int n = 0; n < 5; ++n) {
                    const short8 b = *(const short8*)(
                        Wyp + (size_t)(wv * 80 + n * 16 + fr) * 128 + ks * 32 + fq * 8);
                    acc[0][n] = mfma16(a[0], b, acc[0][n]);
                    acc[1][n] = mfma16(a[1], b, acc[1][n]);
                }
            }
            #pragma unroll
            for (int rf = 0; rf < 2; ++rf)
                #pragma unroll
                for (int n = 0; n < 5; ++n)
                    #pragma unroll
                    for (int j = 0; j < 4; ++j) {
                        const int row = rf * 16 + fq * 4 + j;
                        const int col = wv * 80 + n * 16 + fr;
                        Ys[row][col] = acc[rf][n][j] + (col < 263 ? fc_b[col] : 0.f);
                    }
            __syncthreads();
            float wsum = 0.f;
            #pragma unroll
            for (int s4 = 0; s4 < 4; ++s4) {
                const int jj = wv * 4 + s4;
                const int j = n16 + jj;
                if (j >= B) break;
                bool sw;
                wsum += nll_node(Ys[2 * jj + (lane >> 5)], X, nb + j, lane, sw);
                feat_write(Fnext, Hb + (size_t)j * 256, Cc + (size_t)j * 256,
                           j, sw, lane);
            }
            if (lane == 0) lsum[wv] = wsum;
            __syncthreads();
            if (tid == 0)
                atomicAdd(loss, (lsum[0] + lsum[1] + lsum[2] + lsum[3]) * scale);
            __syncthreads();
        }
        gridbar(barcnt);
    }
}

// ---------------------------------------------------------------------------
extern "C" void kernel_launch(void* const* d_in, const int* in_sizes, int n_in,
                              void* d_out, int out_size, void* d_ws, size_t ws_size,
                              hipStream_t stream)
{
    const float* X       = (const float*)d_in[0];
    const float* Feature = (const float*)d_in[1];
    const float* W_ih_e  = (const float*)d_in[3];
    const float* W_hh_e  = (const float*)d_in[4];
    const float* b_ih_e  = (const float*)d_in[5];
    const float* b_hh_e  = (const float*)d_in[6];
    const float* fc_h_W  = (const float*)d_in[7];
    const float* fc_h_b  = (const float*)d_in[8];
    const float* W_ih_d  = (const float*)d_in[9];
    const float* W_hh_d  = (const float*)d_in[10];
    const float* b_ih_d  = (const float*)d_in[11];
    const float* b_hh_d  = (const float*)d_in[12];
    const float* fc_W    = (const float*)d_in[13];
    const float* fc_b    = (const float*)d_in[14];
    const int Nnodes = in_sizes[0] / 8;   // 262143

    float* out = (float*)d_out;
    hipMemsetAsync(d_out, 0, sizeof(float), stream);

    char* cur = (char*)d_ws;
    auto take = [&](size_t bytes) {
        char* p = cur;
        cur += (bytes + 255) & ~(size_t)255;
        return p;
    };
    ushort* featA = (ushort*)take((size_t)65536 * 256 * 2);
    ushort* featB = (ushort*)take((size_t)32768 * 256 * 2);
    ushort* Wz    = (ushort*)take((size_t)512 * 256 * 2);
    ushort* Wg    = (ushort*)take((size_t)1024 * 576 * 2);
    ushort* Wy    = (ushort*)take((size_t)320 * 128 * 2);
    float*  bg    = (float*) take((size_t)1024 * 4);
    unsigned* bar = (unsigned*)take(256);
    ushort* Xb    = (ushort*)take((size_t)Nnodes * 8 * 2);
    const size_t fixed_used = (size_t)(cur - (char*)d_ws);
    int CB = 65536;
    while (CB > 8192 && fixed_used + (size_t)CB * 2048 + 4096 > ws_size) CB >>= 1;
    ushort* Zb = (ushort*)take((size_t)CB * 512 * 2);
    ushort* Hb = (ushort*)take((size_t)CB * 256 * 2);
    ushort* Cc = (ushort*)take((size_t)CB * 256 * 2);

    hipMemsetAsync(bar, 0, 256, stream);

    const int nx = Nnodes * 8;
    const int packTotal = 131072 + 589824 + 1024 + 40960 + nx;
    pack_all<<<(packTotal + 255) / 256, 256, 0, stream>>>(
        fc_h_W, Wz, W_ih_d, W_hh_d, Wg, b_ih_d, b_hh_d, bg, fc_W, Wy, X, Xb, nx);

    encoder_root<<<1, 256, 0, stream>>>(X, Feature, W_ih_e, W_hh_e, b_ih_e, b_hh_e, featA);

    // levels 0..10: fused multi-block kernel with manual grid barriers
    fused_levels<<<NBLK, 256, 0, stream>>>(
        X, Xb, featA, featB, Wz, fc_h_b, Wg, bg, Wy, fc_b, Hb, Cc, out, bar);

    // levels 11..16: 3-kernel pipeline
    for (int l = 11; l < 17; ++l) {
        const int B = 1 << l;
        const long long nb = B - 1;
        ushort* Fcur  = (l & 1) ? featB : featA;
        ushort* Fnext = (l & 1) ? featA : featB;
        const int writeFeat = (l < 16) ? 1 : 0;
        const float scale = 1.f / ((float)B * 17.f);
        for (int j0 = 0; j0 < B; j0 += CB) {
            const int Bc = (B - j0 < CB) ? (B - j0) : CB;
            const int mg = (Bc + 127) / 128;
            gemm_bf16<1, 1, 256><<<dim3(mg, 4), 256, 0, stream>>>(
                Fcur + (size_t)j0 * 256, 256, Bc - 1,
                Wz, 256, 511,
                fc_h_b, nullptr, Zb, 512, Bc, 512);
            gates_lstm<<<dim3(mg, 8), 256, 0, stream>>>(
                Xb + (size_t)(nb + j0) * 8,
                Fcur + (size_t)j0 * 256,
                Zb, Wg, bg, Hb, Cc, Bc);
            ynll<<<(Bc + 15) / 16, 256, 0, stream>>>(
                Hb, Cc, Wy, fc_b, X,
                (writeFeat ? Fnext + (size_t)2 * j0 * 256 : (ushort*)nullptr), out,
                Bc, nb + j0, scale, writeFeat);
        }
    }
}

// Round 8
// 1458.923 us; speedup vs baseline: 1.2184x; 1.0974x over previous
//
#include <hip/hip_runtime.h>
#include <hip/hip_bf16.h>
#include <math.h>

// ---------------------------------------------------------------------------
// D=256, LVL=17, MIX=20. N nodes = 2^18-1; internal = 2^17-1 = 131071.
//  * Encoder reads ORIGINAL Feature -> only root's encoded feature survives.
//  * Decoder: 17 sequential levels; level l has B=2^l nodes. X_P dead.
// R8: uniform 3-kernel pipeline (z_gemm -> gates_lstm -> ynll) per level with
//     a persistent packed-A buffer Ap[node][576] = [X | F | z_h | 0]:
//       - pack_all prefills X cols + zero pad (once per launch)
//       - parent ynll writes child features into Ap rows (no featA/featB)
//       - z_gemm writes z_h into Ap cols 264..519
//     -> gates_lstm staging is a single branch-free global_load_lds.
//     (R5/R7 lesson: coop launch / manual grid barriers lose to small
//      launches at this work size; R4 structure restored.)
// ---------------------------------------------------------------------------

#define LOG2PI 1.8378770664093453f

typedef __attribute__((ext_vector_type(8))) short short8;
typedef __attribute__((ext_vector_type(4))) float f32x4;

__device__ inline float sigm(float x) { return 1.0f / (1.0f + expf(-x)); }

__device__ inline ushort f2b(float v) {
    union { float f; unsigned u; } x; x.f = v;
    unsigned r = x.u + 0x7fffu + ((x.u >> 16) & 1u);
    return (ushort)(r >> 16);
}
__device__ inline float b2f(ushort h) {
    union { unsigned u; float f; } x; x.u = ((unsigned)h) << 16; return x.f;
}

__device__ inline void gload16(const void* g, void* l) {
    __builtin_amdgcn_global_load_lds(
        (const __attribute__((address_space(1))) unsigned*)g,
        (__attribute__((address_space(3))) unsigned*)l, 16, 0, 0);
}

__device__ inline f32x4 mfma16(short8 a, short8 b, f32x4 c) {
    return __builtin_amdgcn_mfma_f32_16x16x32_bf16(a, b, c, 0, 0, 0);
}

__device__ inline float halfmax(float v) {
    #pragma unroll
    for (int o = 16; o >= 1; o >>= 1) v = fmaxf(v, __shfl_xor(v, o));
    return v;
}
__device__ inline float halfsum(float v) {
    #pragma unroll
    for (int o = 16; o >= 1; o >>= 1) v += __shfl_xor(v, o);
    return v;
}
__device__ inline float lse20(float t) {
    float m = halfmax(t);
    float s = halfsum(expf(t - m));
    return m + logf(s);
}

// NLL for one node; yb = this half's 263-float Y row. Wave-collective.
__device__ inline float nll_node(const float* yb, const float* X,
                                 long long fi, int lane, bool& sw_out)
{
    const int half = lane >> 5, k = lane & 31;
    float v = (k < 20) ? yb[k] : -INFINITY;
    float mm = halfmax(v);
    float se = halfsum((k < 20) ? expf(v - mm) : 0.f);
    float lpi = v - mm - logf(se);
    float mx = 0, my = 0, sx = 1, sy = 1, rho = 0, omr = 1, cxy = 0;
    float ma = 0, mb2 = 0, sa = 1, sb = 1, rab = 0, omr2 = 1, cab = 0;
    float ms = 0, ss2 = 1, csl = 0;
    if (k < 20) {
        mx = yb[20 + k]; my = yb[40 + k];
        float lsx = yb[60 + k], lsy = yb[80 + k];
        sx = expf(lsx); sy = expf(lsy);
        rho = tanhf(yb[100 + k]); omr = 1.f - rho * rho;
        cxy = LOG2PI + lsx + lsy + 0.5f * logf(omr);
        ma = yb[120 + k]; mb2 = yb[140 + k];
        float lsa = yb[160 + k], lsb = yb[180 + k];
        sa = expf(lsa); sb = expf(lsb);
        rab = tanhf(yb[200 + k]); omr2 = 1.f - rab * rab;
        cab = LOG2PI + lsa + lsb + 0.5f * logf(omr2);
        ms = yb[220 + k]; float lss = yb[240 + k];
        ss2 = expf(lss);
        csl = 0.5f * LOG2PI + lss;
    }
    float lq0, lq1, lq2;
    {
        float q0 = yb[260], q1 = yb[261], q2 = yb[262];
        float qm = fmaxf(q0, fmaxf(q1, q2));
        float l = logf(expf(q0 - qm) + expf(q1 - qm) + expf(q2 - qm)) + qm;
        lq0 = q0 - l; lq1 = q1 - l; lq2 = q2 - l;
    }
    const float* pl = X + (size_t)(2 * fi + 1) * 8;
    const float* pr = X + (size_t)(2 * fi + 2) * 8;
    float res[2];
    #pragma unroll
    for (int s = 0; s < 2; ++s) {
        const float* pt = s ? pr : pl;
        float dx = pt[0], dy = pt[1], da = pt[2], db = pt[3], ds = pt[4];
        float t1 = -INFINITY, t2 = -INFINITY, t3 = -INFINITY;
        if (k < 20) {
            float zx = (dx - mx) / sx, zy = (dy - my) / sy;
            float Zz = zx * zx + zy * zy - 2.f * rho * zx * zy;
            t1 = lpi - Zz / (2.f * omr) - cxy;
            float za = (da - ma) / sa, zb = (db - mb2) / sb;
            float Z2 = za * za + zb * zb - 2.f * rab * za * zb;
            t2 = lpi - Z2 / (2.f * omr2) - cab;
            float zs = ds - ms;
            t3 = lpi - (zs * zs) / (2.f * ss2 * ss2) - csl;
        }
        float l1 = lse20(t1), l2 = lse20(t2), l3 = lse20(t3);
        float pen = -(pt[5] * lq0 + pt[6] * lq1 + pt[7] * lq2);
        res[s] = -(l1 + l2 + l3) + pen;
    }
    float Aval = half ? res[1] : res[0];
    float Bval = half ? res[0] : res[1];
    float direct = Aval + __shfl_xor(Aval, 32);
    float swapped = Bval + __shfl_xor(Bval, 32);
    sw_out = swapped < direct;
    return sw_out ? swapped : direct;
}

// Write child features into Ap rows 2fi+1, 2fi+2 (cols 8..263).
__device__ inline void feat_write_ap(ushort* Ap, const ushort* Hj,
                                     const ushort* Cj, long long fi, bool sw,
                                     int lane)
{
    const size_t rowL = 2 * (size_t)fi + 1;
    const int offL = sw ? 128 : 0;
    const int offR = 128 - offL;
    const int part = lane >> 5;
    const int c = (lane & 31) * 4;
    ushort4 vL = *(const ushort4*)((part ? Cj : Hj) + offL + c);
    ushort4 vR = *(const ushort4*)((part ? Cj : Hj) + offR + c);
    *(ushort4*)(Ap + rowL * 576 + 8 + part * 128 + c) = vL;
    *(ushort4*)(Ap + (rowL + 1) * 576 + 8 + part * 128 + c) = vR;
}

// ---------------------------------------------------------------------------
// z_gemm: Z = tanh(F @ Wz^T + fc_h_b), F = Ap chunk cols 8..263 (K=256).
// z_h (cols 0..255) -> Ap cols 264..519; c_f (cols 256..511) -> Zcc[CB][256].
// 128x128 tile, 4 waves, XOR-swizzled LDS. Grid (mg, 4).
// ---------------------------------------------------------------------------
__global__ __launch_bounds__(256) void z_gemm(
    ushort* __restrict__ Apc,          // Ap + (nb+j0)*576
    const ushort* __restrict__ Wz,     // [512][256] bf16
    const float* __restrict__ fc_h_b,
    ushort* __restrict__ Zcc,          // [CB][256] c_f out
    int M)
{
    __shared__ ushort As[128 * 64];
    __shared__ ushort Bs[128 * 64];
    const int tid = threadIdx.x;
    const int lane = tid & 63;
    const int w = tid >> 6;
    const int wr = w >> 1, wc = w & 1;
    const int fr = lane & 15, fq = lane >> 4;
    const int m0 = blockIdx.x * 128, n0 = blockIdx.y * 128;

    f32x4 acc[4][4] = {};

    #pragma unroll
    for (int k0 = 0; k0 < 256; k0 += 64) {
        __syncthreads();
        #pragma unroll
        for (int it = 0; it < 4; ++it) {
            const int i = it * 256 + tid;
            const int row = i >> 3, slot = i & 7;
            const int sl = slot ^ (row & 7);
            const int wbase = (i - lane) * 8;
            {
                int gm = m0 + row; gm = gm < M ? gm : M - 1;
                gload16(Apc + (size_t)gm * 576 + 8 + k0 + sl * 8, &As[wbase]);
            }
            {
                int gn = n0 + row; gn = gn < 512 ? gn : 511;
                gload16(Wz + (size_t)gn * 256 + k0 + sl * 8, &Bs[wbase]);
            }
        }
        __syncthreads();
        #pragma unroll
        for (int ks = 0; ks < 2; ++ks) {
            short8 af[4], bfr[4];
            #pragma unroll
            for (int mr = 0; mr < 4; ++mr) {
                const int row = wr * 64 + mr * 16 + fr;
                const int sl = (ks * 4 + fq) ^ (row & 7);
                af[mr] = *(const short8*)&As[row * 64 + sl * 8];
            }
            #pragma unroll
            for (int nc = 0; nc < 4; ++nc) {
                const int row = wc * 64 + nc * 16 + fr;
                const int sl = (ks * 4 + fq) ^ (row & 7);
                bfr[nc] = *(const short8*)&Bs[row * 64 + sl * 8];
            }
            #pragma unroll
            for (int mr = 0; mr < 4; ++mr)
                #pragma unroll
                for (int nc = 0; nc < 4; ++nc)
                    acc[mr][nc] = mfma16(af[mr], bfr[nc], acc[mr][nc]);
        }
    }

    #pragma unroll
    for (int mr = 0; mr < 4; ++mr) {
        #pragma unroll
        for (int j = 0; j < 4; ++j) {
            const int row = m0 + wr * 64 + mr * 16 + fq * 4 + j;
            if (row >= M) continue;
            #pragma unroll
            for (int nc = 0; nc < 4; ++nc) {
                const int col = n0 + wc * 64 + nc * 16 + fr;
                const float z = tanhf(acc[mr][nc][j] + fc_h_b[col]);
                if (col < 256)
                    Apc[(size_t)row * 576 + 264 + col] = f2b(z);
                else
                    Zcc[(size_t)row * 256 + (col - 256)] = f2b(z);
            }
        }
    }
}

// ---------------------------------------------------------------------------
// gates_lstm: G = Ap[j][0..575] @ Wg^T + bg (K=576, gate-interleaved cols),
// in-register LSTM epilogue -> H,C bf16. Branch-free single-source staging.
// ---------------------------------------------------------------------------
__global__ __launch_bounds__(256) void gates_lstm(
    const ushort* __restrict__ Apc,    // Ap + (nb+j0)*576
    const ushort* __restrict__ Wg,     // [1024][576] interleaved
    const float*  __restrict__ bg,
    const ushort* __restrict__ Zcc,    // [CB][256] c_f
    ushort* __restrict__ H, ushort* __restrict__ C, int M)
{
    __shared__ ushort As[128 * 64];
    __shared__ ushort Bs[128 * 64];
    const int tid = threadIdx.x;
    const int lane = tid & 63;
    const int w = tid >> 6;
    const int wr = w >> 1, wc = w & 1;
    const int fr = lane & 15, fq = lane >> 4;
    const int m0 = blockIdx.x * 128, n0 = blockIdx.y * 128;

    f32x4 acc[4][4] = {};

    #pragma unroll
    for (int k0 = 0; k0 < 576; k0 += 64) {
        __syncthreads();
        #pragma unroll
        for (int it = 0; it < 4; ++it) {
            const int i = it * 256 + tid;
            const int row = i >> 3, slot = i & 7;
            const int sl = slot ^ (row & 7);
            const int wbase = (i - lane) * 8;
            {
                int gm = m0 + row; gm = gm < M ? gm : M - 1;
                gload16(Apc + (size_t)gm * 576 + k0 + sl * 8, &As[wbase]);
            }
            gload16(Wg + (size_t)(n0 + row) * 576 + k0 + sl * 8, &Bs[wbase]);
        }
        __syncthreads();
        #pragma unroll
        for (int ks = 0; ks < 2; ++ks) {
            short8 af[4], bfr[4];
            #pragma unroll
            for (int mr = 0; mr < 4; ++mr) {
                const int row = wr * 64 + mr * 16 + fr;
                const int sl = (ks * 4 + fq) ^ (row & 7);
                af[mr] = *(const short8*)&As[row * 64 + sl * 8];
            }
            #pragma unroll
            for (int nc = 0; nc < 4; ++nc) {
                const int row = wc * 64 + nc * 16 + fr;
                const int sl = (ks * 4 + fq) ^ (row & 7);
                bfr[nc] = *(const short8*)&Bs[row * 64 + sl * 8];
            }
            #pragma unroll
            for (int mr = 0; mr < 4; ++mr)
                #pragma unroll
                for (int nc = 0; nc < 4; ++nc)
                    acc[mr][nc] = mfma16(af[mr], bfr[nc], acc[mr][nc]);
        }
    }

    const int q = fr & 3;
    #pragma unroll
    for (int mr = 0; mr < 4; ++mr) {
        const int node = m0 + wr * 64 + mr * 16 + fq * 4 + q;
        #pragma unroll
        for (int nc = 0; nc < 4; ++nc) {
            const int col = n0 + wc * 64 + nc * 16 + fr;
            f32x4 v = acc[mr][nc];
            const float b = bg[col];
            v[0] += b; v[1] += b; v[2] += b; v[3] += b;
            float gv[4];
            gv[q] = v[q];
            #pragma unroll
            for (int m = 1; m < 4; ++m)
                gv[q ^ m] = __shfl_xor(v[q ^ m], m);
            if (node < M) {
                const int t = (col >> 2) & 255;
                const float cf = b2f(Zcc[(size_t)node * 256 + t]);
                const float c2 = sigm(gv[1]) * cf + sigm(gv[0]) * tanhf(gv[2]);
                const float hv = sigm(gv[3]) * tanhf(c2);
                H[(size_t)node * 256 + t] = f2b(hv);
                C[(size_t)node * 256 + t] = f2b(c2);
            }
        }
    }
}

// ---------------------------------------------------------------------------
// ynll: Y-GEMM + NLL + swap + child-feature write into Ap. Block = 16 nodes.
// ---------------------------------------------------------------------------
__global__ __launch_bounds__(256) void ynll(
    const ushort* __restrict__ Hb, const ushort* __restrict__ Cc,
    const ushort* __restrict__ Wyp,   // [320][128] bf16, rows>=263 zero
    const float* __restrict__ fc_b, const float* __restrict__ X,
    ushort* __restrict__ Ap, float* __restrict__ loss,
    int Bc, long long nb_fi, float scale, int writeFeat)
{
    __shared__ ushort Hs[32 * 128];
    __shared__ float Ys[32][324];
    __shared__ float lsum[4];
    const int tid = threadIdx.x;
    const int lane = tid & 63;
    const int wv = tid >> 6;
    const int fr = lane & 15, fq = lane >> 4;
    const int n16 = blockIdx.x * 16;

    #pragma unroll
    for (int it = 0; it < 2; ++it) {
        const int i = it * 256 + tid;
        const int row = i >> 4, slot = i & 15;
        const int sl = slot ^ (row & 7);
        int gr = n16 * 2 + row;
        const int grmax = 2 * Bc - 1;
        gr = gr <= grmax ? gr : grmax;
        gload16(Hb + (size_t)gr * 128 + sl * 8, &Hs[(i - lane) * 8]);
    }
    __syncthreads();

    f32x4 acc[2][5] = {};
    #pragma unroll
    for (int ks = 0; ks < 4; ++ks) {
        short8 a[2];
        #pragma unroll
        for (int rf = 0; rf < 2; ++rf) {
            const int row = rf * 16 + fr;
            const int sl = (ks * 4 + fq) ^ (row & 7);
            a[rf] = *(const short8*)&Hs[row * 128 + sl * 8];
        }
        #pragma unroll
        for (int n = 0; n < 5; ++n) {
            const short8 b = *(const short8*)(
                Wyp + (size_t)(wv * 80 + n * 16 + fr) * 128 + ks * 32 + fq * 8);
            acc[0][n] = mfma16(a[0], b, acc[0][n]);
            acc[1][n] = mfma16(a[1], b, acc[1][n]);
        }
    }
    #pragma unroll
    for (int rf = 0; rf < 2; ++rf)
        #pragma unroll
        for (int n = 0; n < 5; ++n)
            #pragma unroll
            for (int j = 0; j < 4; ++j) {
                const int row = rf * 16 + fq * 4 + j;
                const int col = wv * 80 + n * 16 + fr;
                Ys[row][col] = acc[rf][n][j] + (col < 263 ? fc_b[col] : 0.f);
            }
    __syncthreads();

    float wsum = 0.f;
    #pragma unroll
    for (int s4 = 0; s4 < 4; ++s4) {
        const int jj = wv * 4 + s4;
        const int j = n16 + jj;
        if (j >= Bc) break;
        bool sw;
        const long long fi = nb_fi + j;
        wsum += nll_node(Ys[2 * jj + (lane >> 5)], X, fi, lane, sw);
        if (writeFeat)
            feat_write_ap(Ap, Hb + (size_t)j * 256, Cc + (size_t)j * 256,
                          fi, sw, lane);
    }
    if (lane == 0) lsum[wv] = wsum;
    __syncthreads();
    if (tid == 0)
        atomicAdd(loss, (lsum[0] + lsum[1] + lsum[2] + lsum[3]) * scale);
}

// ---------------------------------------------------------------------------
// One-time repack + Ap prefill, single launch.
//   Wz[512][256], Wg[1024][576] interleaved, bg[1024], Wy[320][128],
//   Ap[i][0..7] = X[i] bf16, Ap[i][520..575] = 0   (i = internal node id)
// ---------------------------------------------------------------------------
__global__ __launch_bounds__(256) void pack_all(
    const float* __restrict__ fc_h_W, ushort* __restrict__ Wz,
    const float* __restrict__ Wih, const float* __restrict__ Whh,
    ushort* __restrict__ Wg,
    const float* __restrict__ bih, const float* __restrict__ bhh,
    float* __restrict__ bg,
    const float* __restrict__ fcW, ushort* __restrict__ Wy,
    const float* __restrict__ X, ushort* __restrict__ Ap, int nInt)
{
    int i = blockIdx.x * 256 + threadIdx.x;
    if (i < 131072) { Wz[i] = f2b(fc_h_W[i]); return; }
    i -= 131072;
    if (i < 589824) {
        int np = i / 576, c = i - np * 576;
        int n = (np & 3) * 256 + (np >> 2);
        float v = 0.f;
        if (c < 264) v = Wih[n * 264 + c];
        else if (c < 520) v = Whh[n * 256 + (c - 264)];
        Wg[i] = f2b(v);
        return;
    }
    i -= 589824;
    if (i < 1024) {
        int n = (i & 3) * 256 + (i >> 2);
        bg[i] = bih[n] + bhh[n];
        return;
    }
    i -= 1024;
    if (i < 40960) {
        int r = i / 128;
        Wy[i] = f2b(r < 263 ? fcW[i] : 0.f);
        return;
    }
    i -= 40960;
    if (i < nInt * 64) {
        int row = i >> 6, c = i & 63;
        if (c < 8) Ap[(size_t)row * 576 + c] = f2b(X[row * 8 + c]);
        else       Ap[(size_t)row * 576 + 512 + c] = 0;   // cols 520..575
    }
}

// ---------------------------------------------------------------------------
// Encoder: only the root feature matters. One block. Writes Ap[0][8..263].
// ---------------------------------------------------------------------------
__global__ __launch_bounds__(256) void encoder_root(
    const float* __restrict__ X, const float* __restrict__ Feature,
    const float* __restrict__ Wih, const float* __restrict__ Whh,
    const float* __restrict__ bih, const float* __restrict__ bhh,
    ushort* __restrict__ Ap)
{
    __shared__ float gsh[2][512];
    __shared__ float hc[2][256];
    const int t = threadIdx.x;
    for (int ch = 0; ch < 2; ++ch) {
        const int node = 1 + ch;
        const float* x = X + node * 8;
        const float* h = Feature + (size_t)node * 256;
        #pragma unroll
        for (int gi = 0; gi < 2; ++gi) {
            int g = t + gi * 256;
            float s = bih[g] + bhh[g];
            const float* wi = Wih + (size_t)g * 8;
            #pragma unroll
            for (int k = 0; k < 8; ++k) s += wi[k] * x[k];
            const float* wh = Whh + (size_t)g * 128;
            for (int k = 0; k < 128; ++k) s += wh[k] * h[k];
            gsh[ch][g] = s;
        }
    }
    __syncthreads();
    {
        int ch = t >> 7, u = t & 127;
        float i_ = gsh[ch][u], f_ = gsh[ch][128 + u];
        float gg = gsh[ch][256 + u], o_ = gsh[ch][384 + u];
        float c = Feature[(size_t)(1 + ch) * 256 + 128 + u];
        float c2 = sigm(f_) * c + sigm(i_) * tanhf(gg);
        hc[ch][u] = sigm(o_) * tanhf(c2);
        hc[ch][128 + u] = c2;
    }
    __syncthreads();
    Ap[8 + t] = f2b(hc[0][t] + hc[1][t]);
}

// ---------------------------------------------------------------------------
extern "C" void kernel_launch(void* const* d_in, const int* in_sizes, int n_in,
                              void* d_out, int out_size, void* d_ws, size_t ws_size,
                              hipStream_t stream)
{
    const float* X       = (const float*)d_in[0];
    const float* Feature = (const float*)d_in[1];
    const float* W_ih_e  = (const float*)d_in[3];
    const float* W_hh_e  = (const float*)d_in[4];
    const float* b_ih_e  = (const float*)d_in[5];
    const float* b_hh_e  = (const float*)d_in[6];
    const float* fc_h_W  = (const float*)d_in[7];
    const float* fc_h_b  = (const float*)d_in[8];
    const float* W_ih_d  = (const float*)d_in[9];
    const float* W_hh_d  = (const float*)d_in[10];
    const float* b_ih_d  = (const float*)d_in[11];
    const float* b_hh_d  = (const float*)d_in[12];
    const float* fc_W    = (const float*)d_in[13];
    const float* fc_b    = (const float*)d_in[14];
    const int Nnodes = in_sizes[0] / 8;       // 262143
    const int nInt = (Nnodes - 1) / 2;        // 131071 internal nodes

    float* out = (float*)d_out;
    hipMemsetAsync(d_out, 0, sizeof(float), stream);

    char* cur = (char*)d_ws;
    auto take = [&](size_t bytes) {
        char* p = cur;
        cur += (bytes + 255) & ~(size_t)255;
        return p;
    };
    ushort* Ap = (ushort*)take((size_t)(nInt + 1) * 576 * 2);   // ~151 MB
    ushort* Wz = (ushort*)take((size_t)512 * 256 * 2);
    ushort* Wg = (ushort*)take((size_t)1024 * 576 * 2);
    ushort* Wy = (ushort*)take((size_t)320 * 128 * 2);
    float*  bg = (float*) take((size_t)1024 * 4);
    const size_t fixed_used = (size_t)(cur - (char*)d_ws);
    // per-chunk: Zcc 512 + H 512 + C 512 = 1536 B/node
    int CB = 65536;
    while (CB > 8192 && fixed_used + (size_t)CB * 1536 + 4096 > ws_size) CB >>= 1;
    ushort* Zcc = (ushort*)take((size_t)CB * 256 * 2);
    ushort* Hb  = (ushort*)take((size_t)CB * 256 * 2);
    ushort* Cc  = (ushort*)take((size_t)CB * 256 * 2);

    const int packTotal = 131072 + 589824 + 1024 + 40960 + nInt * 64;
    pack_all<<<(packTotal + 255) / 256, 256, 0, stream>>>(
        fc_h_W, Wz, W_ih_d, W_hh_d, Wg, b_ih_d, b_hh_d, bg, fc_W, Wy,
        X, Ap, nInt);

    encoder_root<<<1, 256, 0, stream>>>(X, Feature, W_ih_e, W_hh_e,
                                        b_ih_e, b_hh_e, Ap);

    for (int l = 0; l < 17; ++l) {
        const int B = 1 << l;
        const long long nb = B - 1;
        const int writeFeat = (l < 16) ? 1 : 0;
        const float scale = 1.f / ((float)B * 17.f);
        for (int j0 = 0; j0 < B; j0 += CB) {
            const int Bc = (B - j0 < CB) ? (B - j0) : CB;
            const int mg = (Bc + 127) / 128;
            ushort* Apc = Ap + (size_t)(nb + j0) * 576;
            // Z = tanh(F @ Wz^T + b): z_h -> Ap cols 264.., c_f -> Zcc
            z_gemm<<<dim3(mg, 4), 256, 0, stream>>>(Apc, Wz, fc_h_b, Zcc, Bc);
            // gates + LSTM -> H, C
            gates_lstm<<<dim3(mg, 8), 256, 0, stream>>>(
                Apc, Wg, bg, Zcc, Hb, Cc, Bc);
            // Y + NLL + swap + child features into Ap
            ynll<<<(Bc + 15) / 16, 256, 0, stream>>>(
                Hb, Cc, Wy, fc_b, X, Ap, out,
                Bc, nb + j0, scale, writeFeat);
        }
    }
}

// Round 9
// 1315.621 us; speedup vs baseline: 1.3511x; 1.1089x over previous
//
#include <hip/hip_runtime.h>
#include <hip/hip_bf16.h>
#include <math.h>

// ---------------------------------------------------------------------------
// D=256, LVL=17, MIX=20. N nodes = 2^18-1; internal = 2^17-1 = 131071.
//  * Encoder reads ORIGINAL Feature -> only root's encoded feature survives.
//  * Decoder: 17 sequential levels; level l has B=2^l nodes. X_P dead.
// R9 = R8 (persistent packed-A pipeline) + fast transcendentals:
//   __expf/__logf (HW exp2/log2 pipe), clamped exp-based tanh, rcp-based
//   sigmoid, and all NLL divisions folded into exp(-ls)/rcp multiplies.
//   ynll was 58% VALUBusy on libm expansions (R8 rocprof).
// ---------------------------------------------------------------------------

#define LOG2PI 1.8378770664093453f

typedef __attribute__((ext_vector_type(8))) short short8;
typedef __attribute__((ext_vector_type(4))) float f32x4;

__device__ inline float frcp(float x) { return __builtin_amdgcn_rcpf(x); }
__device__ inline float fexp(float x) { return __expf(x); }
__device__ inline float flog(float x) { return __logf(x); }
__device__ inline float ftanh(float x) {
    float xc = fminf(fmaxf(x, -10.f), 10.f);
    float e = __expf(2.f * xc);
    return (e - 1.f) * frcp(e + 1.f);
}
__device__ inline float sigm(float x) {
    float xc = fminf(fmaxf(x, -30.f), 30.f);
    return frcp(1.f + __expf(-xc));
}

__device__ inline ushort f2b(float v) {
    union { float f; unsigned u; } x; x.f = v;
    unsigned r = x.u + 0x7fffu + ((x.u >> 16) & 1u);
    return (ushort)(r >> 16);
}
__device__ inline float b2f(ushort h) {
    union { unsigned u; float f; } x; x.u = ((unsigned)h) << 16; return x.f;
}

__device__ inline void gload16(const void* g, void* l) {
    __builtin_amdgcn_global_load_lds(
        (const __attribute__((address_space(1))) unsigned*)g,
        (__attribute__((address_space(3))) unsigned*)l, 16, 0, 0);
}

__device__ inline f32x4 mfma16(short8 a, short8 b, f32x4 c) {
    return __builtin_amdgcn_mfma_f32_16x16x32_bf16(a, b, c, 0, 0, 0);
}

__device__ inline float halfmax(float v) {
    #pragma unroll
    for (int o = 16; o >= 1; o >>= 1) v = fmaxf(v, __shfl_xor(v, o));
    return v;
}
__device__ inline float halfsum(float v) {
    #pragma unroll
    for (int o = 16; o >= 1; o >>= 1) v += __shfl_xor(v, o);
    return v;
}
__device__ inline float lse20(float t) {
    float m = halfmax(t);
    float s = halfsum(fexp(t - m));   // t-m <= 0; -inf lanes -> 0
    return m + flog(s);
}

// NLL for one node; yb = this half's 263-float Y row. Wave-collective.
// Divisions eliminated: 1/s* = exp(-ls*), 1/(2(1-rho^2)) via rcp.
__device__ inline float nll_node(const float* yb, const float* X,
                                 long long fi, int lane, bool& sw_out)
{
    const int half = lane >> 5, k = lane & 31;
    float v = (k < 20) ? yb[k] : -INFINITY;
    float mm = halfmax(v);
    float se = halfsum((k < 20) ? fexp(v - mm) : 0.f);
    float lpi = v - mm - flog(se);
    float mx = 0, my = 0, rsx = 1, rsy = 1, rho = 0, hro = 0, cxy = 0;
    float ma = 0, mb2 = 0, rsa = 1, rsb = 1, rab = 0, hra = 0, cab = 0;
    float ms = 0, hrs = 0, csl = 0;
    if (k < 20) {
        mx = yb[20 + k]; my = yb[40 + k];
        float lsx = yb[60 + k], lsy = yb[80 + k];
        rsx = fexp(-lsx); rsy = fexp(-lsy);
        rho = ftanh(yb[100 + k]);
        float omr = 1.f - rho * rho;
        hro = 0.5f * frcp(omr);
        cxy = LOG2PI + lsx + lsy + 0.5f * flog(omr);
        ma = yb[120 + k]; mb2 = yb[140 + k];
        float lsa = yb[160 + k], lsb = yb[180 + k];
        rsa = fexp(-lsa); rsb = fexp(-lsb);
        rab = ftanh(yb[200 + k]);
        float omr2 = 1.f - rab * rab;
        hra = 0.5f * frcp(omr2);
        cab = LOG2PI + lsa + lsb + 0.5f * flog(omr2);
        ms = yb[220 + k]; float lss = yb[240 + k];
        float rss = fexp(-lss);
        hrs = 0.5f * rss * rss;
        csl = 0.5f * LOG2PI + lss;
    }
    float lq0, lq1, lq2;
    {
        float q0 = yb[260], q1 = yb[261], q2 = yb[262];
        float qm = fmaxf(q0, fmaxf(q1, q2));
        float l = flog(fexp(q0 - qm) + fexp(q1 - qm) + fexp(q2 - qm)) + qm;
        lq0 = q0 - l; lq1 = q1 - l; lq2 = q2 - l;
    }
    const float* pl = X + (size_t)(2 * fi + 1) * 8;
    const float* pr = X + (size_t)(2 * fi + 2) * 8;
    float res[2];
    #pragma unroll
    for (int s = 0; s < 2; ++s) {
        const float* pt = s ? pr : pl;
        float dx = pt[0], dy = pt[1], da = pt[2], db = pt[3], ds = pt[4];
        float t1 = -INFINITY, t2 = -INFINITY, t3 = -INFINITY;
        if (k < 20) {
            float zx = (dx - mx) * rsx, zy = (dy - my) * rsy;
            float Zz = zx * zx + zy * zy - 2.f * rho * zx * zy;
            t1 = lpi - Zz * hro - cxy;
            float za = (da - ma) * rsa, zb = (db - mb2) * rsb;
            float Z2 = za * za + zb * zb - 2.f * rab * za * zb;
            t2 = lpi - Z2 * hra - cab;
            float zs = ds - ms;
            t3 = lpi - zs * zs * hrs - csl;
        }
        float l1 = lse20(t1), l2 = lse20(t2), l3 = lse20(t3);
        float pen = -(pt[5] * lq0 + pt[6] * lq1 + pt[7] * lq2);
        res[s] = -(l1 + l2 + l3) + pen;
    }
    float Aval = half ? res[1] : res[0];
    float Bval = half ? res[0] : res[1];
    float direct = Aval + __shfl_xor(Aval, 32);
    float swapped = Bval + __shfl_xor(Bval, 32);
    sw_out = swapped < direct;
    return sw_out ? swapped : direct;
}

// Write child features into Ap rows 2fi+1, 2fi+2 (cols 8..263).
__device__ inline void feat_write_ap(ushort* Ap, const ushort* Hj,
                                     const ushort* Cj, long long fi, bool sw,
                                     int lane)
{
    const size_t rowL = 2 * (size_t)fi + 1;
    const int offL = sw ? 128 : 0;
    const int offR = 128 - offL;
    const int part = lane >> 5;
    const int c = (lane & 31) * 4;
    ushort4 vL = *(const ushort4*)((part ? Cj : Hj) + offL + c);
    ushort4 vR = *(const ushort4*)((part ? Cj : Hj) + offR + c);
    *(ushort4*)(Ap + rowL * 576 + 8 + part * 128 + c) = vL;
    *(ushort4*)(Ap + (rowL + 1) * 576 + 8 + part * 128 + c) = vR;
}

// ---------------------------------------------------------------------------
// z_gemm: Z = tanh(F @ Wz^T + fc_h_b), F = Ap chunk cols 8..263 (K=256).
// z_h -> Ap cols 264..519; c_f -> Zcc[CB][256]. Grid (mg, 4).
// ---------------------------------------------------------------------------
__global__ __launch_bounds__(256) void z_gemm(
    ushort* __restrict__ Apc,
    const ushort* __restrict__ Wz,
    const float* __restrict__ fc_h_b,
    ushort* __restrict__ Zcc,
    int M)
{
    __shared__ ushort As[128 * 64];
    __shared__ ushort Bs[128 * 64];
    const int tid = threadIdx.x;
    const int lane = tid & 63;
    const int w = tid >> 6;
    const int wr = w >> 1, wc = w & 1;
    const int fr = lane & 15, fq = lane >> 4;
    const int m0 = blockIdx.x * 128, n0 = blockIdx.y * 128;

    f32x4 acc[4][4] = {};

    #pragma unroll
    for (int k0 = 0; k0 < 256; k0 += 64) {
        __syncthreads();
        #pragma unroll
        for (int it = 0; it < 4; ++it) {
            const int i = it * 256 + tid;
            const int row = i >> 3, slot = i & 7;
            const int sl = slot ^ (row & 7);
            const int wbase = (i - lane) * 8;
            {
                int gm = m0 + row; gm = gm < M ? gm : M - 1;
                gload16(Apc + (size_t)gm * 576 + 8 + k0 + sl * 8, &As[wbase]);
            }
            {
                int gn = n0 + row; gn = gn < 512 ? gn : 511;
                gload16(Wz + (size_t)gn * 256 + k0 + sl * 8, &Bs[wbase]);
            }
        }
        __syncthreads();
        #pragma unroll
        for (int ks = 0; ks < 2; ++ks) {
            short8 af[4], bfr[4];
            #pragma unroll
            for (int mr = 0; mr < 4; ++mr) {
                const int row = wr * 64 + mr * 16 + fr;
                const int sl = (ks * 4 + fq) ^ (row & 7);
                af[mr] = *(const short8*)&As[row * 64 + sl * 8];
            }
            #pragma unroll
            for (int nc = 0; nc < 4; ++nc) {
                const int row = wc * 64 + nc * 16 + fr;
                const int sl = (ks * 4 + fq) ^ (row & 7);
                bfr[nc] = *(const short8*)&Bs[row * 64 + sl * 8];
            }
            #pragma unroll
            for (int mr = 0; mr < 4; ++mr)
                #pragma unroll
                for (int nc = 0; nc < 4; ++nc)
                    acc[mr][nc] = mfma16(af[mr], bfr[nc], acc[mr][nc]);
        }
    }

    #pragma unroll
    for (int mr = 0; mr < 4; ++mr) {
        #pragma unroll
        for (int j = 0; j < 4; ++j) {
            const int row = m0 + wr * 64 + mr * 16 + fq * 4 + j;
            if (row >= M) continue;
            #pragma unroll
            for (int nc = 0; nc < 4; ++nc) {
                const int col = n0 + wc * 64 + nc * 16 + fr;
                const float z = ftanh(acc[mr][nc][j] + fc_h_b[col]);
                if (col < 256)
                    Apc[(size_t)row * 576 + 264 + col] = f2b(z);
                else
                    Zcc[(size_t)row * 256 + (col - 256)] = f2b(z);
            }
        }
    }
}

// ---------------------------------------------------------------------------
// gates_lstm: G = Ap[j][0..575] @ Wg^T + bg (gate-interleaved), in-register
// LSTM epilogue -> H,C bf16. Branch-free single-source staging.
// ---------------------------------------------------------------------------
__global__ __launch_bounds__(256) void gates_lstm(
    const ushort* __restrict__ Apc,
    const ushort* __restrict__ Wg,
    const float*  __restrict__ bg,
    const ushort* __restrict__ Zcc,
    ushort* __restrict__ H, ushort* __restrict__ C, int M)
{
    __shared__ ushort As[128 * 64];
    __shared__ ushort Bs[128 * 64];
    const int tid = threadIdx.x;
    const int lane = tid & 63;
    const int w = tid >> 6;
    const int wr = w >> 1, wc = w & 1;
    const int fr = lane & 15, fq = lane >> 4;
    const int m0 = blockIdx.x * 128, n0 = blockIdx.y * 128;

    f32x4 acc[4][4] = {};

    #pragma unroll
    for (int k0 = 0; k0 < 576; k0 += 64) {
        __syncthreads();
        #pragma unroll
        for (int it = 0; it < 4; ++it) {
            const int i = it * 256 + tid;
            const int row = i >> 3, slot = i & 7;
            const int sl = slot ^ (row & 7);
            const int wbase = (i - lane) * 8;
            {
                int gm = m0 + row; gm = gm < M ? gm : M - 1;
                gload16(Apc + (size_t)gm * 576 + k0 + sl * 8, &As[wbase]);
            }
            gload16(Wg + (size_t)(n0 + row) * 576 + k0 + sl * 8, &Bs[wbase]);
        }
        __syncthreads();
        #pragma unroll
        for (int ks = 0; ks < 2; ++ks) {
            short8 af[4], bfr[4];
            #pragma unroll
            for (int mr = 0; mr < 4; ++mr) {
                const int row = wr * 64 + mr * 16 + fr;
                const int sl = (ks * 4 + fq) ^ (row & 7);
                af[mr] = *(const short8*)&As[row * 64 + sl * 8];
            }
            #pragma unroll
            for (int nc = 0; nc < 4; ++nc) {
                const int row = wc * 64 + nc * 16 + fr;
                const int sl = (ks * 4 + fq) ^ (row & 7);
                bfr[nc] = *(const short8*)&Bs[row * 64 + sl * 8];
            }
            #pragma unroll
            for (int mr = 0; mr < 4; ++mr)
                #pragma unroll
                for (int nc = 0; nc < 4; ++nc)
                    acc[mr][nc] = mfma16(af[mr], bfr[nc], acc[mr][nc]);
        }
    }

    const int q = fr & 3;
    #pragma unroll
    for (int mr = 0; mr < 4; ++mr) {
        const int node = m0 + wr * 64 + mr * 16 + fq * 4 + q;
        #pragma unroll
        for (int nc = 0; nc < 4; ++nc) {
            const int col = n0 + wc * 64 + nc * 16 + fr;
            f32x4 v = acc[mr][nc];
            const float b = bg[col];
            v[0] += b; v[1] += b; v[2] += b; v[3] += b;
            float gv[4];
            gv[q] = v[q];
            #pragma unroll
            for (int m = 1; m < 4; ++m)
                gv[q ^ m] = __shfl_xor(v[q ^ m], m);
            if (node < M) {
                const int t = (col >> 2) & 255;
                const float cf = b2f(Zcc[(size_t)node * 256 + t]);
                const float c2 = sigm(gv[1]) * cf + sigm(gv[0]) * ftanh(gv[2]);
                const float hv = sigm(gv[3]) * ftanh(c2);
                H[(size_t)node * 256 + t] = f2b(hv);
                C[(size_t)node * 256 + t] = f2b(c2);
            }
        }
    }
}

// ---------------------------------------------------------------------------
// ynll: Y-GEMM + NLL + swap + child-feature write into Ap. Block = 16 nodes.
// ---------------------------------------------------------------------------
__global__ __launch_bounds__(256) void ynll(
    const ushort* __restrict__ Hb, const ushort* __restrict__ Cc,
    const ushort* __restrict__ Wyp,
    const float* __restrict__ fc_b, const float* __restrict__ X,
    ushort* __restrict__ Ap, float* __restrict__ loss,
    int Bc, long long nb_fi, float scale, int writeFeat)
{
    __shared__ ushort Hs[32 * 128];
    __shared__ float Ys[32][324];
    __shared__ float lsum[4];
    const int tid = threadIdx.x;
    const int lane = tid & 63;
    const int wv = tid >> 6;
    const int fr = lane & 15, fq = lane >> 4;
    const int n16 = blockIdx.x * 16;

    #pragma unroll
    for (int it = 0; it < 2; ++it) {
        const int i = it * 256 + tid;
        const int row = i >> 4, slot = i & 15;
        const int sl = slot ^ (row & 7);
        int gr = n16 * 2 + row;
        const int grmax = 2 * Bc - 1;
        gr = gr <= grmax ? gr : grmax;
        gload16(Hb + (size_t)gr * 128 + sl * 8, &Hs[(i - lane) * 8]);
    }
    __syncthreads();

    f32x4 acc[2][5] = {};
    #pragma unroll
    for (int ks = 0; ks < 4; ++ks) {
        short8 a[2];
        #pragma unroll
        for (int rf = 0; rf < 2; ++rf) {
            const int row = rf * 16 + fr;
            const int sl = (ks * 4 + fq) ^ (row & 7);
            a[rf] = *(const short8*)&Hs[row * 128 + sl * 8];
        }
        #pragma unroll
        for (int n = 0; n < 5; ++n) {
            const short8 b = *(const short8*)(
                Wyp + (size_t)(wv * 80 + n * 16 + fr) * 128 + ks * 32 + fq * 8);
            acc[0][n] = mfma16(a[0], b, acc[0][n]);
            acc[1][n] = mfma16(a[1], b, acc[1][n]);
        }
    }
    #pragma unroll
    for (int rf = 0; rf < 2; ++rf)
        #pragma unroll
        for (int n = 0; n < 5; ++n)
            #pragma unroll
            for (int j = 0; j < 4; ++j) {
                const int row = rf * 16 + fq * 4 + j;
                const int col = wv * 80 + n * 16 + fr;
                Ys[row][col] = acc[rf][n][j] + (col < 263 ? fc_b[col] : 0.f);
            }
    __syncthreads();

    float wsum = 0.f;
    #pragma unroll
    for (int s4 = 0; s4 < 4; ++s4) {
        const int jj = wv * 4 + s4;
        const int j = n16 + jj;
        if (j >= Bc) break;
        bool sw;
        const long long fi = nb_fi + j;
        wsum += nll_node(Ys[2 * jj + (lane >> 5)], X, fi, lane, sw);
        if (writeFeat)
            feat_write_ap(Ap, Hb + (size_t)j * 256, Cc + (size_t)j * 256,
                          fi, sw, lane);
    }
    if (lane == 0) lsum[wv] = wsum;
    __syncthreads();
    if (tid == 0)
        atomicAdd(loss, (lsum[0] + lsum[1] + lsum[2] + lsum[3]) * scale);
}

// ---------------------------------------------------------------------------
// One-time repack + Ap prefill, single launch.
// ---------------------------------------------------------------------------
__global__ __launch_bounds__(256) void pack_all(
    const float* __restrict__ fc_h_W, ushort* __restrict__ Wz,
    const float* __restrict__ Wih, const float* __restrict__ Whh,
    ushort* __restrict__ Wg,
    const float* __restrict__ bih, const float* __restrict__ bhh,
    float* __restrict__ bg,
    const float* __restrict__ fcW, ushort* __restrict__ Wy,
    const float* __restrict__ X, ushort* __restrict__ Ap, int nInt)
{
    int i = blockIdx.x * 256 + threadIdx.x;
    if (i < 131072) { Wz[i] = f2b(fc_h_W[i]); return; }
    i -= 131072;
    if (i < 589824) {
        int np = i / 576, c = i - np * 576;
        int n = (np & 3) * 256 + (np >> 2);
        float v = 0.f;
        if (c < 264) v = Wih[n * 264 + c];
        else if (c < 520) v = Whh[n * 256 + (c - 264)];
        Wg[i] = f2b(v);
        return;
    }
    i -= 589824;
    if (i < 1024) {
        int n = (i & 3) * 256 + (i >> 2);
        bg[i] = bih[n] + bhh[n];
        return;
    }
    i -= 1024;
    if (i < 40960) {
        int r = i / 128;
        Wy[i] = f2b(r < 263 ? fcW[i] : 0.f);
        return;
    }
    i -= 40960;
    if (i < nInt * 64) {
        int row = i >> 6, c = i & 63;
        if (c < 8) Ap[(size_t)row * 576 + c] = f2b(X[row * 8 + c]);
        else       Ap[(size_t)row * 576 + 512 + c] = 0;   // cols 520..575
    }
}

// ---------------------------------------------------------------------------
// Encoder: only the root feature matters. One block. Writes Ap[0][8..263].
// ---------------------------------------------------------------------------
__global__ __launch_bounds__(256) void encoder_root(
    const float* __restrict__ X, const float* __restrict__ Feature,
    const float* __restrict__ Wih, const float* __restrict__ Whh,
    const float* __restrict__ bih, const float* __restrict__ bhh,
    ushort* __restrict__ Ap)
{
    __shared__ float gsh[2][512];
    __shared__ float hc[2][256];
    const int t = threadIdx.x;
    for (int ch = 0; ch < 2; ++ch) {
        const int node = 1 + ch;
        const float* x = X + node * 8;
        const float* h = Feature + (size_t)node * 256;
        #pragma unroll
        for (int gi = 0; gi < 2; ++gi) {
            int g = t + gi * 256;
            float s = bih[g] + bhh[g];
            const float* wi = Wih + (size_t)g * 8;
            #pragma unroll
            for (int k = 0; k < 8; ++k) s += wi[k] * x[k];
            const float* wh = Whh + (size_t)g * 128;
            for (int k = 0; k < 128; ++k) s += wh[k] * h[k];
            gsh[ch][g] = s;
        }
    }
    __syncthreads();
    {
        int ch = t >> 7, u = t & 127;
        float i_ = gsh[ch][u], f_ = gsh[ch][128 + u];
        float gg = gsh[ch][256 + u], o_ = gsh[ch][384 + u];
        float c = Feature[(size_t)(1 + ch) * 256 + 128 + u];
        float c2 = sigm(f_) * c + sigm(i_) * ftanh(gg);
        hc[ch][u] = sigm(o_) * ftanh(c2);
        hc[ch][128 + u] = c2;
    }
    __syncthreads();
    Ap[8 + t] = f2b(hc[0][t] + hc[1][t]);
}

// ---------------------------------------------------------------------------
extern "C" void kernel_launch(void* const* d_in, const int* in_sizes, int n_in,
                              void* d_out, int out_size, void* d_ws, size_t ws_size,
                              hipStream_t stream)
{
    const float* X       = (const float*)d_in[0];
    const float* Feature = (const float*)d_in[1];
    const float* W_ih_e  = (const float*)d_in[3];
    const float* W_hh_e  = (const float*)d_in[4];
    const float* b_ih_e  = (const float*)d_in[5];
    const float* b_hh_e  = (const float*)d_in[6];
    const float* fc_h_W  = (const float*)d_in[7];
    const float* fc_h_b  = (const float*)d_in[8];
    const float* W_ih_d  = (const float*)d_in[9];
    const float* W_hh_d  = (const float*)d_in[10];
    const float* b_ih_d  = (const float*)d_in[11];
    const float* b_hh_d  = (const float*)d_in[12];
    const float* fc_W    = (const float*)d_in[13];
    const float* fc_b    = (const float*)d_in[14];
    const int Nnodes = in_sizes[0] / 8;       // 262143
    const int nInt = (Nnodes - 1) / 2;        // 131071 internal nodes

    float* out = (float*)d_out;
    hipMemsetAsync(d_out, 0, sizeof(float), stream);

    char* cur = (char*)d_ws;
    auto take = [&](size_t bytes) {
        char* p = cur;
        cur += (bytes + 255) & ~(size_t)255;
        return p;
    };
    ushort* Ap = (ushort*)take((size_t)(nInt + 1) * 576 * 2);   // ~151 MB
    ushort* Wz = (ushort*)take((size_t)512 * 256 * 2);
    ushort* Wg = (ushort*)take((size_t)1024 * 576 * 2);
    ushort* Wy = (ushort*)take((size_t)320 * 128 * 2);
    float*  bg = (float*) take((size_t)1024 * 4);
    const size_t fixed_used = (size_t)(cur - (char*)d_ws);
    int CB = 65536;
    while (CB > 8192 && fixed_used + (size_t)CB * 1536 + 4096 > ws_size) CB >>= 1;
    ushort* Zcc = (ushort*)take((size_t)CB * 256 * 2);
    ushort* Hb  = (ushort*)take((size_t)CB * 256 * 2);
    ushort* Cc  = (ushort*)take((size_t)CB * 256 * 2);

    const int packTotal = 131072 + 589824 + 1024 + 40960 + nInt * 64;
    pack_all<<<(packTotal + 255) / 256, 256, 0, stream>>>(
        fc_h_W, Wz, W_ih_d, W_hh_d, Wg, b_ih_d, b_hh_d, bg, fc_W, Wy,
        X, Ap, nInt);

    encoder_root<<<1, 256, 0, stream>>>(X, Feature, W_ih_e, W_hh_e,
                                        b_ih_e, b_hh_e, Ap);

    for (int l = 0; l < 17; ++l) {
        const int B = 1 << l;
        const long long nb = B - 1;
        const int writeFeat = (l < 16) ? 1 : 0;
        const float scale = 1.f / ((float)B * 17.f);
        for (int j0 = 0; j0 < B; j0 += CB) {
            const int Bc = (B - j0 < CB) ? (B - j0) : CB;
            const int mg = (Bc + 127) / 128;
            ushort* Apc = Ap + (size_t)(nb + j0) * 576;
            z_gemm<<<dim3(mg, 4), 256, 0, stream>>>(Apc, Wz, fc_h_b, Zcc, Bc);
            gates_lstm<<<dim3(mg, 8), 256, 0, stream>>>(
                Apc, Wg, bg, Zcc, Hb, Cc, Bc);
            ynll<<<(Bc + 15) / 16, 256, 0, stream>>>(
                Hb, Cc, Wy, fc_b, X, Ap, out,
                Bc, nb + j0, scale, writeFeat);
        }
    }
}